// Round 1
// baseline (1706.450 us; speedup 1.0000x reference)
//
#include <hip/hip_runtime.h>
#include <hip/hip_bf16.h>
#include <stdint.h>

// RGCN (basis decomposition, mean agg, root weight + bias)
// Pipeline: deg histogram -> prefix scan -> CSR fill -> per-node aggregation
// (no float atomics) -> f32 GEMM [N,1152]x[1152,128].

#define CHUNK 2048  // elements per scan block (256 thr x 8)

// --- K1: degree histogram ------------------------------------------------
__global__ void k_deg(const int* __restrict__ dst, int E, int* __restrict__ deg) {
    int e = blockIdx.x * blockDim.x + threadIdx.x;
    if (e < E) atomicAdd(&deg[dst[e]], 1);
}

// --- K2a: local inclusive scan over 2048-element chunks ------------------
__global__ __launch_bounds__(256) void k_scan_local(const int* __restrict__ deg, int N,
                                                    int* __restrict__ tmp,
                                                    int* __restrict__ blockSum) {
    __shared__ int tot[256];
    int base = blockIdx.x * CHUNK + threadIdx.x * 8;
    int v[8];
    int s = 0;
    for (int j = 0; j < 8; j++) {
        int idx = base + j;
        int d = (idx < N) ? deg[idx] : 0;
        s += d;
        v[j] = s;
    }
    tot[threadIdx.x] = s;
    __syncthreads();
    // Hillis-Steele inclusive scan over 256 thread totals
    for (int off = 1; off < 256; off <<= 1) {
        int t = (threadIdx.x >= (unsigned)off) ? tot[threadIdx.x - off] : 0;
        __syncthreads();
        tot[threadIdx.x] += t;
        __syncthreads();
    }
    int excl = (threadIdx.x > 0) ? tot[threadIdx.x - 1] : 0;
    for (int j = 0; j < 8; j++) {
        int idx = base + j;
        if (idx < N) tmp[idx] = v[j] + excl;
    }
    if (threadIdx.x == 255) blockSum[blockIdx.x] = tot[255];
}

// --- K2b: scan of per-chunk sums (nChunks <= 256, single thread) ----------
__global__ void k_scan_blocks(int* blockSum, int nb) {
    if (blockIdx.x == 0 && threadIdx.x == 0) {
        int run = 0;
        for (int i = 0; i < nb; i++) {
            int v = blockSum[i];
            blockSum[i] = run;   // exclusive
            run += v;
        }
    }
}

// --- K2c: finalize row_ptr (inclusive -> row_ptr[i+1]) + cursor -----------
__global__ void k_finalize(const int* __restrict__ tmp, const int* __restrict__ blockOff,
                           const int* __restrict__ deg, int N,
                           int* __restrict__ row_ptr, int* __restrict__ cursor) {
    int i = blockIdx.x * blockDim.x + threadIdx.x;
    if (i < N) {
        int incl = tmp[i] + blockOff[i >> 11];
        row_ptr[i + 1] = incl;
        cursor[i] = incl - deg[i];   // exclusive start
    }
    if (i == 0) row_ptr[0] = 0;
}

// --- K3: fill CSR (packed src*16 | etype) ---------------------------------
__global__ void k_fill(const int* __restrict__ src, const int* __restrict__ dstA,
                       const int* __restrict__ et, int E,
                       int* __restrict__ cursor, int* __restrict__ csr) {
    int e = blockIdx.x * blockDim.x + threadIdx.x;
    if (e < E) {
        int d = dstA[e];
        int slot = atomicAdd(&cursor[d], 1);
        csr[slot] = (src[e] << 4) | (et[e] & 15);
    }
}

// --- K4: per-node aggregation (block = node, 256 thr) ----------------------
// thread t: channel c = t&127, basis half bh = t>>7 (owns bases bh*4..bh*4+3)
__global__ __launch_bounds__(256) void k_agg(const float* __restrict__ x,
                                             const float* __restrict__ comp,
                                             const int* __restrict__ row_ptr,
                                             const int* __restrict__ csr,
                                             __hip_bfloat16* __restrict__ agg) {
    __shared__ float scomp[128];   // comp is [16,8]
    int t = threadIdx.x;
    if (t < 128) scomp[t] = comp[t];
    __syncthreads();

    int i = blockIdx.x;
    int c = t & 127;
    int bh = t >> 7;
    int s0 = row_ptr[i], s1 = row_ptr[i + 1];
    float a0 = 0.f, a1 = 0.f, a2 = 0.f, a3 = 0.f;
    for (int j = s0; j < s1; j++) {
        int p = csr[j];
        int src = p >> 4;
        int et = p & 15;
        float xv = x[src * 128 + c];
        const float* cf = &scomp[et * 8 + bh * 4];
        a0 += cf[0] * xv;
        a1 += cf[1] * xv;
        a2 += cf[2] * xv;
        a3 += cf[3] * xv;
    }
    float inv = 1.0f / fmaxf((float)(s1 - s0), 1.0f);
    int base = i * 1024 + bh * 512 + c;
    agg[base      ] = __float2bfloat16(a0 * inv);
    agg[base + 128] = __float2bfloat16(a1 * inv);
    agg[base + 256] = __float2bfloat16(a2 * inv);
    agg[base + 384] = __float2bfloat16(a3 * inv);
}

// --- K5: GEMM out[N,128] = [agg(bf16) | x(f32)] @ W[1152,128] + bias -------
// BM=128 rows/block, 256 threads: thread tile 8 rows x 8 cols.
__global__ __launch_bounds__(256) void k_gemm(const __hip_bfloat16* __restrict__ agg,
                                              const float* __restrict__ x,
                                              const float* __restrict__ W,
                                              const float* __restrict__ bias,
                                              float* __restrict__ out, int N) {
    __shared__ float fT[128][33];
    __shared__ float wT[32][128];
    int i0 = blockIdx.x * 128;
    int t = threadIdx.x;
    int tx = t & 15;   // col group: cols tx*8 .. +7
    int ty = t >> 4;   // row group: rows ty*8 .. +7

    float acc[8][8];
    #pragma unroll
    for (int r = 0; r < 8; r++)
        #pragma unroll
        for (int c = 0; c < 8; c++) acc[r][c] = 0.f;

    for (int k0 = 0; k0 < 1152; k0 += 32) {
        // stage feat tile 128x32 (cols k0..k0+31)
        #pragma unroll
        for (int j = 0; j < 16; j++) {
            int el = t + j * 256;       // 0..4095
            int r = el >> 5, kk = el & 31;
            int row = i0 + r, k = k0 + kk;
            float v = 0.f;
            if (row < N) {
                if (k < 1024) v = __bfloat162float(agg[row * 1024 + k]);
                else          v = x[row * 128 + (k - 1024)];
            }
            fT[r][kk] = v;
        }
        // stage W tile 32x128
        #pragma unroll
        for (int j = 0; j < 16; j++) {
            int el = t + j * 256;       // 0..4095
            int kk = el >> 7, oc = el & 127;
            wT[kk][oc] = W[(k0 + kk) * 128 + oc];
        }
        __syncthreads();
        #pragma unroll
        for (int kk = 0; kk < 32; kk++) {
            float4 w0 = *(const float4*)&wT[kk][tx * 8];
            float4 w1 = *(const float4*)&wT[kk][tx * 8 + 4];
            #pragma unroll
            for (int rr = 0; rr < 8; rr++) {
                float fv = fT[ty * 8 + rr][kk];
                acc[rr][0] += fv * w0.x; acc[rr][1] += fv * w0.y;
                acc[rr][2] += fv * w0.z; acc[rr][3] += fv * w0.w;
                acc[rr][4] += fv * w1.x; acc[rr][5] += fv * w1.y;
                acc[rr][6] += fv * w1.z; acc[rr][7] += fv * w1.w;
            }
        }
        __syncthreads();
    }

    float4 b0 = *(const float4*)&bias[tx * 8];
    float4 b1 = *(const float4*)&bias[tx * 8 + 4];
    #pragma unroll
    for (int rr = 0; rr < 8; rr++) {
        int row = i0 + ty * 8 + rr;
        if (row < N) {
            float4 o0, o1;
            o0.x = acc[rr][0] + b0.x; o0.y = acc[rr][1] + b0.y;
            o0.z = acc[rr][2] + b0.z; o0.w = acc[rr][3] + b0.w;
            o1.x = acc[rr][4] + b1.x; o1.y = acc[rr][5] + b1.y;
            o1.z = acc[rr][6] + b1.z; o1.w = acc[rr][7] + b1.w;
            *(float4*)&out[row * 128 + tx * 8]     = o0;
            *(float4*)&out[row * 128 + tx * 8 + 4] = o1;
        }
    }
}

extern "C" void kernel_launch(void* const* d_in, const int* in_sizes, int n_in,
                              void* d_out, int out_size, void* d_ws, size_t ws_size,
                              hipStream_t stream) {
    const float* x      = (const float*)d_in[0];   // [N,128]
    const float* weight = (const float*)d_in[1];   // [9,128,128] flat = [1152,128]
    const float* comp   = (const float*)d_in[2];   // [16,8]
    const float* bias   = (const float*)d_in[3];   // [128]
    const int*   eidx   = (const int*)d_in[4];     // [2,E]
    const int*   etype  = (const int*)d_in[5];     // [E]

    int N = in_sizes[0] / 128;
    int E = in_sizes[5];
    const int* srcA = eidx;
    const int* dstA = eidx + E;

    // workspace layout (256B aligned)
    uint8_t* ws = (uint8_t*)d_ws;
    size_t off = 0;
    auto take = [&](size_t bytes) -> void* {
        void* p = ws + off;
        off = (off + bytes + 255) & ~(size_t)255;
        return p;
    };
    __hip_bfloat16* agg = (__hip_bfloat16*)take((size_t)N * 1024 * sizeof(__hip_bfloat16));
    int* deg     = (int*)take((size_t)N * sizeof(int));
    int* tmp     = (int*)take((size_t)N * sizeof(int));
    int* row_ptr = (int*)take((size_t)(N + 1) * sizeof(int));
    int* cursor  = (int*)take((size_t)N * sizeof(int));
    int* bsum    = (int*)take(256 * sizeof(int));
    int* csr     = (int*)take((size_t)E * sizeof(int));
    (void)ws_size;

    int nChunks = (N + CHUNK - 1) / CHUNK;

    hipMemsetAsync(deg, 0, (size_t)N * sizeof(int), stream);

    k_deg<<<(E + 255) / 256, 256, 0, stream>>>(dstA, E, deg);
    k_scan_local<<<nChunks, 256, 0, stream>>>(deg, N, tmp, bsum);
    k_scan_blocks<<<1, 64, 0, stream>>>(bsum, nChunks);
    k_finalize<<<(N + 255) / 256, 256, 0, stream>>>(tmp, bsum, deg, N, row_ptr, cursor);
    k_fill<<<(E + 255) / 256, 256, 0, stream>>>(srcA, dstA, etype, E, cursor, csr);
    k_agg<<<N, 256, 0, stream>>>(x, comp, row_ptr, csr, agg);
    k_gemm<<<(N + 127) / 128, 256, 0, stream>>>(agg, x, weight, bias, (float*)d_out, N);
}

// Round 2
// 521.086 us; speedup vs baseline: 3.2748x; 3.2748x over previous
//
#include <hip/hip_runtime.h>
#include <hip/hip_bf16.h>
#include <stdint.h>

// RGCN (basis decomposition, mean agg, root weight + bias)
// Pipeline: deg histogram -> prefix scan -> CSR fill -> per-node aggregation
// writing bf16 feat[N,1152] -> bf16 MFMA GEMM [N,1152]x[1152,128] (f32 acc).

#define CHUNK 2048  // elements per scan block (256 thr x 8)

typedef __attribute__((ext_vector_type(8))) __bf16 bf16x8;
typedef __attribute__((ext_vector_type(4))) float f32x4;

// --- K1: degree histogram ------------------------------------------------
__global__ void k_deg(const int* __restrict__ dst, int E, int* __restrict__ deg) {
    int e = blockIdx.x * blockDim.x + threadIdx.x;
    if (e < E) atomicAdd(&deg[dst[e]], 1);
}

// --- K2a: local inclusive scan over 2048-element chunks ------------------
__global__ __launch_bounds__(256) void k_scan_local(const int* __restrict__ deg, int N,
                                                    int* __restrict__ tmp,
                                                    int* __restrict__ blockSum) {
    __shared__ int tot[256];
    int base = blockIdx.x * CHUNK + threadIdx.x * 8;
    int v[8];
    int s = 0;
    for (int j = 0; j < 8; j++) {
        int idx = base + j;
        int d = (idx < N) ? deg[idx] : 0;
        s += d;
        v[j] = s;
    }
    tot[threadIdx.x] = s;
    __syncthreads();
    for (int off = 1; off < 256; off <<= 1) {
        int t = (threadIdx.x >= (unsigned)off) ? tot[threadIdx.x - off] : 0;
        __syncthreads();
        tot[threadIdx.x] += t;
        __syncthreads();
    }
    int excl = (threadIdx.x > 0) ? tot[threadIdx.x - 1] : 0;
    for (int j = 0; j < 8; j++) {
        int idx = base + j;
        if (idx < N) tmp[idx] = v[j] + excl;
    }
    if (threadIdx.x == 255) blockSum[blockIdx.x] = tot[255];
}

// --- K2b: scan of per-chunk sums (nChunks <= 256) -------------------------
__global__ void k_scan_blocks(int* blockSum, int nb) {
    if (blockIdx.x == 0 && threadIdx.x == 0) {
        int run = 0;
        for (int i = 0; i < nb; i++) {
            int v = blockSum[i];
            blockSum[i] = run;   // exclusive
            run += v;
        }
    }
}

// --- K2c: finalize row_ptr + cursor ---------------------------------------
__global__ void k_finalize(const int* __restrict__ tmp, const int* __restrict__ blockOff,
                           const int* __restrict__ deg, int N,
                           int* __restrict__ row_ptr, int* __restrict__ cursor) {
    int i = blockIdx.x * blockDim.x + threadIdx.x;
    if (i < N) {
        int incl = tmp[i] + blockOff[i >> 11];
        row_ptr[i + 1] = incl;
        cursor[i] = incl - deg[i];
    }
    if (i == 0) row_ptr[0] = 0;
}

// --- K3: fill CSR (packed src*16 | etype) ---------------------------------
__global__ void k_fill(const int* __restrict__ src, const int* __restrict__ dstA,
                       const int* __restrict__ et, int E,
                       int* __restrict__ cursor, int* __restrict__ csr) {
    int e = blockIdx.x * blockDim.x + threadIdx.x;
    if (e < E) {
        int d = dstA[e];
        int slot = atomicAdd(&cursor[d], 1);
        csr[slot] = (src[e] << 4) | (et[e] & 15);
    }
}

// --- K4: per-node aggregation -> bf16 feat row [1152] ----------------------
// block = 1 node, 128 threads; thread t owns channel t for all 8 bases.
__global__ __launch_bounds__(128) void k_agg(const float* __restrict__ x,
                                             const float* __restrict__ comp,
                                             const int* __restrict__ row_ptr,
                                             const int* __restrict__ csr,
                                             __hip_bfloat16* __restrict__ feat) {
    __shared__ float scomp[128];   // comp is [16,8]
    int t = threadIdx.x;
    scomp[t] = comp[t];
    __syncthreads();

    int i = blockIdx.x;
    int s0 = row_ptr[i], s1 = row_ptr[i + 1];
    float a[8];
    #pragma unroll
    for (int b = 0; b < 8; b++) a[b] = 0.f;

    for (int j = s0; j < s1; j++) {
        int p = csr[j];
        float xv = x[(size_t)(p >> 4) * 128 + t];
        const float* cf = &scomp[(p & 15) * 8];
        #pragma unroll
        for (int b = 0; b < 8; b++) a[b] += cf[b] * xv;
    }
    float inv = 1.0f / fmaxf((float)(s1 - s0), 1.0f);
    __hip_bfloat16* fr = feat + (size_t)i * 1152;
    #pragma unroll
    for (int b = 0; b < 8; b++) fr[b * 128 + t] = __float2bfloat16(a[b] * inv);
    fr[1024 + t] = __float2bfloat16(x[(size_t)i * 128 + t]);
}

// --- K5a: W[1152,128] f32 -> bf16 fragment layout Wf[kb][hi][n][j] ---------
__global__ void k_wprep(const float* __restrict__ W, __hip_bfloat16* __restrict__ Wf) {
    int idx = blockIdx.x * 256 + threadIdx.x;
    if (idx >= 1152 * 128) return;
    int k = idx >> 7, n = idx & 127;
    int kb = k >> 5, hi = (k >> 3) & 3, j = k & 7;
    Wf[((((kb << 2) + hi) << 7 | n) << 3) | j] = __float2bfloat16(W[idx]);
}

// --- K5b: MFMA GEMM out[M,128] = feat[M,1152] @ W + bias -------------------
// 256 thr = 4 waves; wave w: rows [blk*128 + w*32, +32), all 128 cols.
// Per wave: 2 row-tiles x 8 col-tiles of 16x16, K-steps of 32.
__global__ __launch_bounds__(256) void k_gemm_mfma(const __hip_bfloat16* __restrict__ feat,
                                                   const __hip_bfloat16* __restrict__ Wf,
                                                   const float* __restrict__ bias,
                                                   float* __restrict__ out, int M) {
    int t = threadIdx.x;
    int wid = t >> 6, lane = t & 63;
    int lo = lane & 15, hi = lane >> 4;
    int rbase = blockIdx.x * 128 + wid * 32;

    f32x4 acc[2][8];
    #pragma unroll
    for (int mt = 0; mt < 2; mt++)
        #pragma unroll
        for (int nt = 0; nt < 8; nt++) acc[mt][nt] = (f32x4){0.f, 0.f, 0.f, 0.f};

    const bf16x8* fv = (const bf16x8*)feat;
    const bf16x8* wv = (const bf16x8*)Wf;

    int r0 = rbase + lo;       if (r0 >= M) r0 = M - 1;
    int r1 = rbase + 16 + lo;  if (r1 >= M) r1 = M - 1;
    const bf16x8* arow0 = fv + (size_t)r0 * 144 + hi;   // 144 = 1152/8 vecs per row
    const bf16x8* arow1 = fv + (size_t)r1 * 144 + hi;

    float bs[8];
    #pragma unroll
    for (int nt = 0; nt < 8; nt++) bs[nt] = bias[nt * 16 + lo];

    for (int kb = 0; kb < 36; kb++) {
        bf16x8 a0 = arow0[kb * 4];
        bf16x8 a1 = arow1[kb * 4];
        const bf16x8* wb = wv + (((kb << 2) + hi) << 7) + lo;
        #pragma unroll
        for (int nt = 0; nt < 8; nt++) {
            bf16x8 b = wb[nt * 16];
            acc[0][nt] = __builtin_amdgcn_mfma_f32_16x16x32_bf16(a0, b, acc[0][nt], 0, 0, 0);
            acc[1][nt] = __builtin_amdgcn_mfma_f32_16x16x32_bf16(a1, b, acc[1][nt], 0, 0, 0);
        }
    }

    // C/D layout: col = lane&15, row = (lane>>4)*4 + q   [verified m89/m91]
    #pragma unroll
    for (int mt = 0; mt < 2; mt++) {
        #pragma unroll
        for (int q = 0; q < 4; q++) {
            int row = rbase + mt * 16 + hi * 4 + q;
            if (row < M) {
                float* orow = out + (size_t)row * 128;
                #pragma unroll
                for (int nt = 0; nt < 8; nt++)
                    orow[nt * 16 + lo] = acc[mt][nt][q] + bs[nt];
            }
        }
    }
}

extern "C" void kernel_launch(void* const* d_in, const int* in_sizes, int n_in,
                              void* d_out, int out_size, void* d_ws, size_t ws_size,
                              hipStream_t stream) {
    const float* x      = (const float*)d_in[0];   // [N,128]
    const float* weight = (const float*)d_in[1];   // [9,128,128] = [1152,128]
    const float* comp   = (const float*)d_in[2];   // [16,8]
    const float* bias   = (const float*)d_in[3];   // [128]
    const int*   eidx   = (const int*)d_in[4];     // [2,E]
    const int*   etype  = (const int*)d_in[5];     // [E]

    int N = in_sizes[0] / 128;
    int E = in_sizes[5];
    const int* srcA = eidx;
    const int* dstA = eidx + E;

    uint8_t* ws = (uint8_t*)d_ws;
    size_t off = 0;
    auto take = [&](size_t bytes) -> void* {
        void* p = ws + off;
        off = (off + bytes + 255) & ~(size_t)255;
        return p;
    };
    __hip_bfloat16* feat = (__hip_bfloat16*)take((size_t)N * 1152 * sizeof(__hip_bfloat16));
    __hip_bfloat16* Wf   = (__hip_bfloat16*)take((size_t)1152 * 128 * sizeof(__hip_bfloat16));
    int* deg     = (int*)take((size_t)N * sizeof(int));
    int* tmp     = (int*)take((size_t)N * sizeof(int));
    int* row_ptr = (int*)take((size_t)(N + 1) * sizeof(int));
    int* cursor  = (int*)take((size_t)N * sizeof(int));
    int* bsum    = (int*)take(256 * sizeof(int));
    int* csr     = (int*)take((size_t)E * sizeof(int));
    (void)ws_size;

    int nChunks = (N + CHUNK - 1) / CHUNK;

    hipMemsetAsync(deg, 0, (size_t)N * sizeof(int), stream);

    k_deg<<<(E + 255) / 256, 256, 0, stream>>>(dstA, E, deg);
    k_wprep<<<(1152 * 128 + 255) / 256, 256, 0, stream>>>(weight, Wf);
    k_scan_local<<<nChunks, 256, 0, stream>>>(deg, N, tmp, bsum);
    k_scan_blocks<<<1, 64, 0, stream>>>(bsum, nChunks);
    k_finalize<<<(N + 255) / 256, 256, 0, stream>>>(tmp, bsum, deg, N, row_ptr, cursor);
    k_fill<<<(E + 255) / 256, 256, 0, stream>>>(srcA, dstA, etype, E, cursor, csr);
    k_agg<<<N, 128, 0, stream>>>(x, comp, row_ptr, csr, feat);
    k_gemm_mfma<<<(N + 127) / 128, 256, 0, stream>>>(feat, Wf, bias, (float*)d_out, N);
}

// Round 3
// 449.512 us; speedup vs baseline: 3.7962x; 1.1592x over previous
//
#include <hip/hip_runtime.h>
#include <hip/hip_bf16.h>
#include <stdint.h>

// RGCN (basis decomposition, mean agg, root weight + bias)
// Pipeline: deg histogram -> prefix scan -> CSR fill -> FUSED
// (per-node aggregation in registers -> LDS feat tile -> bf16 MFMA GEMM).

#define CHUNK 2048   // elements per scan block (256 thr x 8)
#define FPAD 1160    // LDS feat row stride in bf16 (1152 + 8 pad: banks 2-way)

typedef __attribute__((ext_vector_type(8))) __bf16 bf16x8;
typedef __attribute__((ext_vector_type(4))) float f32x4;

// --- K1: degree histogram ------------------------------------------------
__global__ void k_deg(const int* __restrict__ dst, int E, int* __restrict__ deg) {
    int e = blockIdx.x * blockDim.x + threadIdx.x;
    if (e < E) atomicAdd(&deg[dst[e]], 1);
}

// --- K2a: local inclusive scan over 2048-element chunks ------------------
__global__ __launch_bounds__(256) void k_scan_local(const int* __restrict__ deg, int N,
                                                    int* __restrict__ tmp,
                                                    int* __restrict__ blockSum) {
    __shared__ int tot[256];
    int base = blockIdx.x * CHUNK + threadIdx.x * 8;
    int v[8];
    int s = 0;
    for (int j = 0; j < 8; j++) {
        int idx = base + j;
        int d = (idx < N) ? deg[idx] : 0;
        s += d;
        v[j] = s;
    }
    tot[threadIdx.x] = s;
    __syncthreads();
    for (int off = 1; off < 256; off <<= 1) {
        int t = (threadIdx.x >= (unsigned)off) ? tot[threadIdx.x - off] : 0;
        __syncthreads();
        tot[threadIdx.x] += t;
        __syncthreads();
    }
    int excl = (threadIdx.x > 0) ? tot[threadIdx.x - 1] : 0;
    for (int j = 0; j < 8; j++) {
        int idx = base + j;
        if (idx < N) tmp[idx] = v[j] + excl;
    }
    if (threadIdx.x == 255) blockSum[blockIdx.x] = tot[255];
}

// --- K2b: scan of per-chunk sums (nChunks <= 256) -------------------------
__global__ void k_scan_blocks(int* blockSum, int nb) {
    if (blockIdx.x == 0 && threadIdx.x == 0) {
        int run = 0;
        for (int i = 0; i < nb; i++) {
            int v = blockSum[i];
            blockSum[i] = run;   // exclusive
            run += v;
        }
    }
}

// --- K2c: finalize row_ptr + cursor ---------------------------------------
__global__ void k_finalize(const int* __restrict__ tmp, const int* __restrict__ blockOff,
                           const int* __restrict__ deg, int N,
                           int* __restrict__ row_ptr, int* __restrict__ cursor) {
    int i = blockIdx.x * blockDim.x + threadIdx.x;
    if (i < N) {
        int incl = tmp[i] + blockOff[i >> 11];
        row_ptr[i + 1] = incl;
        cursor[i] = incl - deg[i];
    }
    if (i == 0) row_ptr[0] = 0;
}

// --- K3: fill CSR (packed src*16 | etype) ---------------------------------
__global__ void k_fill(const int* __restrict__ src, const int* __restrict__ dstA,
                       const int* __restrict__ et, int E,
                       int* __restrict__ cursor, int* __restrict__ csr) {
    int e = blockIdx.x * blockDim.x + threadIdx.x;
    if (e < E) {
        int d = dstA[e];
        int slot = atomicAdd(&cursor[d], 1);
        csr[slot] = (src[e] << 4) | (et[e] & 15);
    }
}

// --- K4a: x (f32) -> xb (bf16), vectorized ---------------------------------
__global__ __launch_bounds__(256) void k_xb(const float* __restrict__ x,
                                            __hip_bfloat16* __restrict__ xb, int n4) {
    int i = blockIdx.x * 256 + threadIdx.x;
    if (i >= n4) return;
    float4 v = ((const float4*)x)[i];
    __hip_bfloat16 h0 = __float2bfloat16(v.x), h1 = __float2bfloat16(v.y);
    __hip_bfloat16 h2 = __float2bfloat16(v.z), h3 = __float2bfloat16(v.w);
    uint32_t p0 = ((uint32_t)*(uint16_t*)&h1 << 16) | *(uint16_t*)&h0;
    uint32_t p1 = ((uint32_t)*(uint16_t*)&h3 << 16) | *(uint16_t*)&h2;
    ((uint2*)xb)[i] = make_uint2(p0, p1);
}

// --- K4b: W[1152,128] f32 -> bf16 fragment layout Wf[kb][hi][n][j] ---------
__global__ void k_wprep(const float* __restrict__ W, __hip_bfloat16* __restrict__ Wf) {
    int idx = blockIdx.x * 256 + threadIdx.x;
    if (idx >= 1152 * 128) return;
    int k = idx >> 7, n = idx & 127;
    int kb = k >> 5, hi = (k >> 3) & 3, j = k & 7;
    Wf[((((kb << 2) + hi) << 7 | n) << 3) | j] = __float2bfloat16(W[idx]);
}

// --- K5: FUSED aggregation + MFMA GEMM -------------------------------------
// Block = 16 nodes, 256 thr = 4 waves.
// Phase 1: wave w aggregates nodes w*4..w*4+3 (1 wave/node, 2 ch/lane),
//          writes bf16 feat rows [agg(1024) | root x(128)] to LDS.
// Phase 2: 16x1152 @ 1152x128 MFMA; wave w owns col-tiles 2w, 2w+1.
__global__ __launch_bounds__(256) void k_fused(const __hip_bfloat16* __restrict__ xb,
                                               const float* __restrict__ comp,
                                               const int* __restrict__ row_ptr,
                                               const int* __restrict__ csr,
                                               const __hip_bfloat16* __restrict__ Wf,
                                               const float* __restrict__ bias,
                                               float* __restrict__ out, int M) {
    __shared__ __hip_bfloat16 fl[16][FPAD];
    __shared__ float scomp[128];   // comp [16,8]
    int t = threadIdx.x;
    if (t < 128) scomp[t] = comp[t];
    int wid = t >> 6, lane = t & 63;
    int i0 = blockIdx.x * 16;
    __syncthreads();

    // ---- phase 1: aggregate ----
    for (int r = 0; r < 4; r++) {
        int lr = wid * 4 + r;
        int i = i0 + lr;
        float a[8][2];
        #pragma unroll
        for (int b = 0; b < 8; b++) { a[b][0] = 0.f; a[b][1] = 0.f; }
        int s0 = 0, s1 = 0;
        if (i < M) { s0 = row_ptr[i]; s1 = row_ptr[i + 1]; }
        #pragma unroll 2
        for (int j = s0; j < s1; j++) {
            int p = csr[j];
            int src = p >> 4, et = p & 15;
            uint32_t raw = *(const uint32_t*)(xb + (size_t)src * 128 + lane * 2);
            float x0 = __uint_as_float(raw << 16);
            float x1 = __uint_as_float(raw & 0xffff0000u);
            const f32x4* cf = (const f32x4*)&scomp[et * 8];
            f32x4 c0 = cf[0], c1 = cf[1];
            a[0][0] += c0.x * x0; a[0][1] += c0.x * x1;
            a[1][0] += c0.y * x0; a[1][1] += c0.y * x1;
            a[2][0] += c0.z * x0; a[2][1] += c0.z * x1;
            a[3][0] += c0.w * x0; a[3][1] += c0.w * x1;
            a[4][0] += c1.x * x0; a[4][1] += c1.x * x1;
            a[5][0] += c1.y * x0; a[5][1] += c1.y * x1;
            a[6][0] += c1.z * x0; a[6][1] += c1.z * x1;
            a[7][0] += c1.w * x0; a[7][1] += c1.w * x1;
        }
        float inv = 1.0f / fmaxf((float)(s1 - s0), 1.0f);
        #pragma unroll
        for (int b = 0; b < 8; b++) {
            __hip_bfloat16 h0 = __float2bfloat16(a[b][0] * inv);
            __hip_bfloat16 h1 = __float2bfloat16(a[b][1] * inv);
            uint32_t pk = ((uint32_t)*(uint16_t*)&h1 << 16) | *(uint16_t*)&h0;
            *(uint32_t*)&fl[lr][b * 128 + lane * 2] = pk;
        }
        uint32_t rr = (i < M) ? *(const uint32_t*)(xb + (size_t)i * 128 + lane * 2) : 0u;
        *(uint32_t*)&fl[lr][1024 + lane * 2] = rr;
    }
    __syncthreads();

    // ---- phase 2: MFMA ----
    int lo = lane & 15, hi = lane >> 4;
    f32x4 acc0 = (f32x4){0.f, 0.f, 0.f, 0.f};
    f32x4 acc1 = (f32x4){0.f, 0.f, 0.f, 0.f};
    const bf16x8* wv = (const bf16x8*)Wf;
    int nt0 = wid * 2, nt1 = wid * 2 + 1;
    for (int kb = 0; kb < 36; kb++) {
        bf16x8 afrag = *(const bf16x8*)&fl[lo][kb * 32 + hi * 8];
        const bf16x8* wb = wv + (((kb << 2) + hi) << 7) + lo;
        acc0 = __builtin_amdgcn_mfma_f32_16x16x32_bf16(afrag, wb[nt0 * 16], acc0, 0, 0, 0);
        acc1 = __builtin_amdgcn_mfma_f32_16x16x32_bf16(afrag, wb[nt1 * 16], acc1, 0, 0, 0);
    }
    float b0 = bias[nt0 * 16 + lo], b1 = bias[nt1 * 16 + lo];
    #pragma unroll
    for (int q = 0; q < 4; q++) {
        int row = i0 + hi * 4 + q;   // C/D: col=lane&15, row=(lane>>4)*4+q
        if (row < M) {
            out[(size_t)row * 128 + nt0 * 16 + lo] = acc0[q] + b0;
            out[(size_t)row * 128 + nt1 * 16 + lo] = acc1[q] + b1;
        }
    }
}

extern "C" void kernel_launch(void* const* d_in, const int* in_sizes, int n_in,
                              void* d_out, int out_size, void* d_ws, size_t ws_size,
                              hipStream_t stream) {
    const float* x      = (const float*)d_in[0];   // [N,128]
    const float* weight = (const float*)d_in[1];   // [9,128,128] = [1152,128]
    const float* comp   = (const float*)d_in[2];   // [16,8]
    const float* bias   = (const float*)d_in[3];   // [128]
    const int*   eidx   = (const int*)d_in[4];     // [2,E]
    const int*   etype  = (const int*)d_in[5];     // [E]

    int N = in_sizes[0] / 128;
    int E = in_sizes[5];
    const int* srcA = eidx;
    const int* dstA = eidx + E;

    uint8_t* ws = (uint8_t*)d_ws;
    size_t off = 0;
    auto take = [&](size_t bytes) -> void* {
        void* p = ws + off;
        off = (off + bytes + 255) & ~(size_t)255;
        return p;
    };
    __hip_bfloat16* xb = (__hip_bfloat16*)take((size_t)N * 128 * sizeof(__hip_bfloat16));
    __hip_bfloat16* Wf = (__hip_bfloat16*)take((size_t)1152 * 128 * sizeof(__hip_bfloat16));
    int* deg     = (int*)take((size_t)N * sizeof(int));
    int* tmp     = (int*)take((size_t)N * sizeof(int));
    int* row_ptr = (int*)take((size_t)(N + 1) * sizeof(int));
    int* cursor  = (int*)take((size_t)N * sizeof(int));
    int* bsum    = (int*)take(256 * sizeof(int));
    int* csr     = (int*)take((size_t)E * sizeof(int));
    (void)ws_size;

    int nChunks = (N + CHUNK - 1) / CHUNK;

    hipMemsetAsync(deg, 0, (size_t)N * sizeof(int), stream);

    k_deg<<<(E + 255) / 256, 256, 0, stream>>>(dstA, E, deg);
    k_xb<<<(N * 128 / 4 + 255) / 256, 256, 0, stream>>>(x, xb, N * 128 / 4);
    k_wprep<<<(1152 * 128 + 255) / 256, 256, 0, stream>>>(weight, Wf);
    k_scan_local<<<nChunks, 256, 0, stream>>>(deg, N, tmp, bsum);
    k_scan_blocks<<<1, 64, 0, stream>>>(bsum, nChunks);
    k_finalize<<<(N + 255) / 256, 256, 0, stream>>>(tmp, bsum, deg, N, row_ptr, cursor);
    k_fill<<<(E + 255) / 256, 256, 0, stream>>>(srcA, dstA, etype, E, cursor, csr);
    k_fused<<<(N + 15) / 16, 256, 0, stream>>>(xb, comp, row_ptr, csr, Wf, bias,
                                               (float*)d_out, N);
}

// Round 4
// 335.027 us; speedup vs baseline: 5.0935x; 1.3417x over previous
//
#include <hip/hip_runtime.h>
#include <hip/hip_bf16.h>
#include <stdint.h>

// RGCN (basis decomposition, mean agg, root weight + bias)
// Pipeline: prep (xb cast + W frag + deg/rank) -> scan -> finalize ->
// fill (atomic-free) -> FUSED (8-deep batched gather agg -> LDS -> MFMA GEMM).

#define CHUNK 2048   // elements per scan block (256 thr x 8)
#define FPAD 1160    // LDS feat row stride in bf16

typedef __attribute__((ext_vector_type(8))) __bf16 bf16x8;
typedef __attribute__((ext_vector_type(4))) float f32x4;

// --- K1: fused prep: xb cast | W fragment pack | deg histogram + rank ------
__global__ __launch_bounds__(256) void k_prep(const float* __restrict__ x,
                                              __hip_bfloat16* __restrict__ xb, int n4,
                                              const float* __restrict__ W,
                                              __hip_bfloat16* __restrict__ Wf,
                                              const int* __restrict__ dst, int E,
                                              int* __restrict__ deg,
                                              uint8_t* __restrict__ rank,
                                              int xbB, int wpB) {
    int b = blockIdx.x;
    if (b < xbB) {
        int i = b * 256 + threadIdx.x;
        if (i < n4) {
            float4 v = ((const float4*)x)[i];
            __hip_bfloat16 h0 = __float2bfloat16(v.x), h1 = __float2bfloat16(v.y);
            __hip_bfloat16 h2 = __float2bfloat16(v.z), h3 = __float2bfloat16(v.w);
            uint32_t p0 = ((uint32_t)*(uint16_t*)&h1 << 16) | *(uint16_t*)&h0;
            uint32_t p1 = ((uint32_t)*(uint16_t*)&h3 << 16) | *(uint16_t*)&h2;
            ((uint2*)xb)[i] = make_uint2(p0, p1);
        }
    } else if (b < xbB + wpB) {
        int idx = (b - xbB) * 256 + threadIdx.x;
        if (idx < 1152 * 128) {
            int k = idx >> 7, n = idx & 127;
            int kb = k >> 5, hi = (k >> 3) & 3, j = k & 7;
            Wf[((((kb << 2) + hi) << 7 | n) << 3) | j] = __float2bfloat16(W[idx]);
        }
    } else {
        int e0 = ((b - xbB - wpB) * 256 + threadIdx.x) * 4;
        if (e0 + 3 < E) {
            int4 d4 = *(const int4*)(dst + e0);
            uchar4 r;
            r.x = (uint8_t)atomicAdd(&deg[d4.x], 1);
            r.y = (uint8_t)atomicAdd(&deg[d4.y], 1);
            r.z = (uint8_t)atomicAdd(&deg[d4.z], 1);
            r.w = (uint8_t)atomicAdd(&deg[d4.w], 1);
            *(uchar4*)(rank + e0) = r;
        } else {
            for (int e = e0; e < E; e++)
                rank[e] = (uint8_t)atomicAdd(&deg[dst[e]], 1);
        }
    }
}

// --- K2a: local inclusive scan over 2048-element chunks ------------------
__global__ __launch_bounds__(256) void k_scan_local(const int* __restrict__ deg, int N,
                                                    int* __restrict__ tmp,
                                                    int* __restrict__ blockSum) {
    __shared__ int tot[256];
    int base = blockIdx.x * CHUNK + threadIdx.x * 8;
    int v[8];
    int s = 0;
    for (int j = 0; j < 8; j++) {
        int idx = base + j;
        int d = (idx < N) ? deg[idx] : 0;
        s += d;
        v[j] = s;
    }
    tot[threadIdx.x] = s;
    __syncthreads();
    for (int off = 1; off < 256; off <<= 1) {
        int t = (threadIdx.x >= (unsigned)off) ? tot[threadIdx.x - off] : 0;
        __syncthreads();
        tot[threadIdx.x] += t;
        __syncthreads();
    }
    int excl = (threadIdx.x > 0) ? tot[threadIdx.x - 1] : 0;
    for (int j = 0; j < 8; j++) {
        int idx = base + j;
        if (idx < N) tmp[idx] = v[j] + excl;
    }
    if (threadIdx.x == 255) blockSum[blockIdx.x] = tot[255];
}

// --- K2b: finalize row_ptr; chunk offset computed inline (wave reduce) -----
__global__ __launch_bounds__(256) void k_finalize(const int* __restrict__ tmp,
                                                  const int* __restrict__ bsum,
                                                  int N, int* __restrict__ row_ptr) {
    int chunk = (blockIdx.x * 256) >> 11;   // same for whole block
    __shared__ int soff;
    if (threadIdx.x < 64) {
        int v = 0;
        for (int l = threadIdx.x; l < chunk; l += 64) v += bsum[l];
        #pragma unroll
        for (int o = 32; o > 0; o >>= 1) v += __shfl_down(v, o);
        if (threadIdx.x == 0) soff = v;
    }
    __syncthreads();
    int i = blockIdx.x * 256 + threadIdx.x;
    if (i < N) row_ptr[i + 1] = tmp[i] + soff;
    if (i == 0) row_ptr[0] = 0;
}

// --- K3: fill CSR, atomic-free: slot = row_ptr[dst] + rank -----------------
__global__ __launch_bounds__(256) void k_fill(const int* __restrict__ src,
                                              const int* __restrict__ dstA,
                                              const int* __restrict__ et,
                                              const uint8_t* __restrict__ rank,
                                              const int* __restrict__ row_ptr, int E,
                                              int* __restrict__ csr) {
    int e0 = (blockIdx.x * 256 + threadIdx.x) * 4;
    if (e0 + 3 < E) {
        int4 s = *(const int4*)(src + e0);
        int4 d = *(const int4*)(dstA + e0);
        int4 t = *(const int4*)(et + e0);
        uchar4 r = *(const uchar4*)(rank + e0);
        csr[row_ptr[d.x] + r.x] = (s.x << 4) | (t.x & 15);
        csr[row_ptr[d.y] + r.y] = (s.y << 4) | (t.y & 15);
        csr[row_ptr[d.z] + r.z] = (s.z << 4) | (t.z & 15);
        csr[row_ptr[d.w] + r.w] = (s.w << 4) | (t.w & 15);
    } else {
        for (int e = e0; e < E; e++)
            csr[row_ptr[dstA[e]] + rank[e]] = (src[e] << 4) | (et[e] & 15);
    }
}

// --- K4: FUSED aggregation + MFMA GEMM -------------------------------------
// Block = 16 nodes, 256 thr = 4 waves.
// Phase 1: wave w aggregates nodes w*4..w*4+3 (2 ch/lane), 8-edge batches
//          with 8 gathers in flight; writes bf16 feat rows to LDS.
// Phase 2: 16x1152 @ 1152x128 MFMA; wave w owns col-tiles 2w, 2w+1.
__global__ __launch_bounds__(256) void k_fused(const __hip_bfloat16* __restrict__ xb,
                                               const float* __restrict__ comp,
                                               const int* __restrict__ row_ptr,
                                               const int* __restrict__ csr,
                                               const __hip_bfloat16* __restrict__ Wf,
                                               const float* __restrict__ bias,
                                               float* __restrict__ out, int M) {
    __shared__ __hip_bfloat16 fl[16][FPAD];
    __shared__ float scomp[128];   // comp [16,8]
    int t = threadIdx.x;
    if (t < 128) scomp[t] = comp[t];
    int wid = t >> 6, lane = t & 63;
    int i0 = blockIdx.x * 16;
    __syncthreads();

    // ---- phase 1: aggregate ----
    for (int r = 0; r < 4; r++) {
        int lr = wid * 4 + r;
        int i = i0 + lr;
        float a[8][2];
        #pragma unroll
        for (int b = 0; b < 8; b++) { a[b][0] = 0.f; a[b][1] = 0.f; }
        int s0 = 0, s1 = 0;
        if (i < M) { s0 = row_ptr[i]; s1 = row_ptr[i + 1]; }

        auto fma_edge = [&](int p, uint32_t raw) {
            float x0 = __uint_as_float(raw << 16);
            float x1 = __uint_as_float(raw & 0xffff0000u);
            const f32x4* cf = (const f32x4*)&scomp[(p & 15) * 8];
            f32x4 c0 = cf[0], c1 = cf[1];
            a[0][0] += c0.x * x0; a[0][1] += c0.x * x1;
            a[1][0] += c0.y * x0; a[1][1] += c0.y * x1;
            a[2][0] += c0.z * x0; a[2][1] += c0.z * x1;
            a[3][0] += c0.w * x0; a[3][1] += c0.w * x1;
            a[4][0] += c1.x * x0; a[4][1] += c1.x * x1;
            a[5][0] += c1.y * x0; a[5][1] += c1.y * x1;
            a[6][0] += c1.z * x0; a[6][1] += c1.z * x1;
            a[7][0] += c1.w * x0; a[7][1] += c1.w * x1;
        };

        int j = s0;
        for (; j + 8 <= s1; j += 8) {
            int p[8];
            #pragma unroll
            for (int k = 0; k < 8; k++) p[k] = csr[j + k];
            uint32_t rw[8];
            #pragma unroll
            for (int k = 0; k < 8; k++)
                rw[k] = *(const uint32_t*)(xb + (size_t)(p[k] >> 4) * 128 + lane * 2);
            #pragma unroll
            for (int k = 0; k < 8; k++) fma_edge(p[k], rw[k]);
        }
        for (; j < s1; j++) {
            int p = csr[j];
            uint32_t raw = *(const uint32_t*)(xb + (size_t)(p >> 4) * 128 + lane * 2);
            fma_edge(p, raw);
        }

        float inv = 1.0f / fmaxf((float)(s1 - s0), 1.0f);
        #pragma unroll
        for (int b = 0; b < 8; b++) {
            __hip_bfloat16 h0 = __float2bfloat16(a[b][0] * inv);
            __hip_bfloat16 h1 = __float2bfloat16(a[b][1] * inv);
            uint32_t pk = ((uint32_t)*(uint16_t*)&h1 << 16) | *(uint16_t*)&h0;
            *(uint32_t*)&fl[lr][b * 128 + lane * 2] = pk;
        }
        uint32_t rr = (i < M) ? *(const uint32_t*)(xb + (size_t)i * 128 + lane * 2) : 0u;
        *(uint32_t*)&fl[lr][1024 + lane * 2] = rr;
    }
    __syncthreads();

    // ---- phase 2: MFMA ----
    int lo = lane & 15, hi = lane >> 4;
    f32x4 acc0 = (f32x4){0.f, 0.f, 0.f, 0.f};
    f32x4 acc1 = (f32x4){0.f, 0.f, 0.f, 0.f};
    const bf16x8* wv = (const bf16x8*)Wf;
    int nt0 = wid * 2, nt1 = wid * 2 + 1;
    for (int kb = 0; kb < 36; kb++) {
        bf16x8 afrag = *(const bf16x8*)&fl[lo][kb * 32 + hi * 8];
        const bf16x8* wb = wv + (((kb << 2) + hi) << 7) + lo;
        acc0 = __builtin_amdgcn_mfma_f32_16x16x32_bf16(afrag, wb[nt0 * 16], acc0, 0, 0, 0);
        acc1 = __builtin_amdgcn_mfma_f32_16x16x32_bf16(afrag, wb[nt1 * 16], acc1, 0, 0, 0);
    }
    float b0 = bias[nt0 * 16 + lo], b1 = bias[nt1 * 16 + lo];
    #pragma unroll
    for (int q = 0; q < 4; q++) {
        int row = i0 + hi * 4 + q;   // C/D: col=lane&15, row=(lane>>4)*4+q
        if (row < M) {
            out[(size_t)row * 128 + nt0 * 16 + lo] = acc0[q] + b0;
            out[(size_t)row * 128 + nt1 * 16 + lo] = acc1[q] + b1;
        }
    }
}

extern "C" void kernel_launch(void* const* d_in, const int* in_sizes, int n_in,
                              void* d_out, int out_size, void* d_ws, size_t ws_size,
                              hipStream_t stream) {
    const float* x      = (const float*)d_in[0];   // [N,128]
    const float* weight = (const float*)d_in[1];   // [9,128,128] = [1152,128]
    const float* comp   = (const float*)d_in[2];   // [16,8]
    const float* bias   = (const float*)d_in[3];   // [128]
    const int*   eidx   = (const int*)d_in[4];     // [2,E]
    const int*   etype  = (const int*)d_in[5];     // [E]

    int N = in_sizes[0] / 128;
    int E = in_sizes[5];
    const int* srcA = eidx;
    const int* dstA = eidx + E;

    uint8_t* ws = (uint8_t*)d_ws;
    size_t off = 0;
    auto take = [&](size_t bytes) -> void* {
        void* p = ws + off;
        off = (off + bytes + 255) & ~(size_t)255;
        return p;
    };
    __hip_bfloat16* xb = (__hip_bfloat16*)take((size_t)N * 128 * sizeof(__hip_bfloat16));
    __hip_bfloat16* Wf = (__hip_bfloat16*)take((size_t)1152 * 128 * sizeof(__hip_bfloat16));
    int* deg      = (int*)take((size_t)N * sizeof(int));
    int* tmp      = (int*)take((size_t)N * sizeof(int));
    int* row_ptr  = (int*)take((size_t)(N + 1) * sizeof(int));
    int* bsum     = (int*)take(256 * sizeof(int));
    uint8_t* rank = (uint8_t*)take((size_t)E * sizeof(uint8_t));
    int* csr      = (int*)take((size_t)E * sizeof(int));
    (void)ws_size;

    int n4 = N * 128 / 4;
    int xbB = (n4 + 255) / 256;
    int wpB = (1152 * 128 + 255) / 256;
    int dgB = ((E + 3) / 4 + 255) / 256;
    int nChunks = (N + CHUNK - 1) / CHUNK;

    hipMemsetAsync(deg, 0, (size_t)N * sizeof(int), stream);
    k_prep<<<xbB + wpB + dgB, 256, 0, stream>>>(x, xb, n4, weight, Wf, dstA, E,
                                                deg, rank, xbB, wpB);
    k_scan_local<<<nChunks, 256, 0, stream>>>(deg, N, tmp, bsum);
    k_finalize<<<(N + 255) / 256, 256, 0, stream>>>(tmp, bsum, N, row_ptr);
    k_fill<<<((E + 3) / 4 + 255) / 256, 256, 0, stream>>>(srcA, dstA, etype, rank,
                                                          row_ptr, E, csr);
    k_fused<<<(N + 15) / 16, 256, 0, stream>>>(xb, comp, row_ptr, csr, Wf, bias,
                                               (float*)d_out, N);
}

// Round 5
// 330.695 us; speedup vs baseline: 5.1602x; 1.0131x over previous
//
#include <hip/hip_runtime.h>
#include <hip/hip_bf16.h>
#include <stdint.h>

// RGCN (basis decomposition, mean agg, root weight + bias)
// Pipeline: prep (xb cast + W frag + deg/rank) -> scan -> finalize ->
// fill (atomic-free) -> FUSED (double-buffered 8-batch gather agg -> LDS ->
// bf16 MFMA GEMM). 512-thr blocks, 8 waves, forced VGPR<=64 for 32 waves/CU.

#define CHUNK 2048   // elements per scan block (256 thr x 8)
#define FPAD 1160    // LDS feat row stride in bf16

typedef __attribute__((ext_vector_type(8))) __bf16 bf16x8;
typedef __attribute__((ext_vector_type(4))) float f32x4;

// --- K1: fused prep: xb cast | W fragment pack | deg histogram + rank ------
__global__ __launch_bounds__(256) void k_prep(const float* __restrict__ x,
                                              __hip_bfloat16* __restrict__ xb, int n4,
                                              const float* __restrict__ W,
                                              __hip_bfloat16* __restrict__ Wf,
                                              const int* __restrict__ dst, int E,
                                              int* __restrict__ deg,
                                              uint8_t* __restrict__ rank,
                                              int xbB, int wpB) {
    int b = blockIdx.x;
    if (b < xbB) {
        int i = b * 256 + threadIdx.x;
        if (i < n4) {
            float4 v = ((const float4*)x)[i];
            __hip_bfloat16 h0 = __float2bfloat16(v.x), h1 = __float2bfloat16(v.y);
            __hip_bfloat16 h2 = __float2bfloat16(v.z), h3 = __float2bfloat16(v.w);
            uint32_t p0 = ((uint32_t)*(uint16_t*)&h1 << 16) | *(uint16_t*)&h0;
            uint32_t p1 = ((uint32_t)*(uint16_t*)&h3 << 16) | *(uint16_t*)&h2;
            ((uint2*)xb)[i] = make_uint2(p0, p1);
        }
    } else if (b < xbB + wpB) {
        int idx = (b - xbB) * 256 + threadIdx.x;
        if (idx < 1152 * 128) {
            int k = idx >> 7, n = idx & 127;
            int kb = k >> 5, hi = (k >> 3) & 3, j = k & 7;
            Wf[((((kb << 2) + hi) << 7 | n) << 3) | j] = __float2bfloat16(W[idx]);
        }
    } else {
        int e0 = ((b - xbB - wpB) * 256 + threadIdx.x) * 4;
        if (e0 + 3 < E) {
            int4 d4 = *(const int4*)(dst + e0);
            uchar4 r;
            r.x = (uint8_t)atomicAdd(&deg[d4.x], 1);
            r.y = (uint8_t)atomicAdd(&deg[d4.y], 1);
            r.z = (uint8_t)atomicAdd(&deg[d4.z], 1);
            r.w = (uint8_t)atomicAdd(&deg[d4.w], 1);
            *(uchar4*)(rank + e0) = r;
        } else {
            for (int e = e0; e < E; e++)
                rank[e] = (uint8_t)atomicAdd(&deg[dst[e]], 1);
        }
    }
}

// --- K2a: local inclusive scan over 2048-element chunks ------------------
__global__ __launch_bounds__(256) void k_scan_local(const int* __restrict__ deg, int N,
                                                    int* __restrict__ tmp,
                                                    int* __restrict__ blockSum) {
    __shared__ int tot[256];
    int base = blockIdx.x * CHUNK + threadIdx.x * 8;
    int v[8];
    int s = 0;
    for (int j = 0; j < 8; j++) {
        int idx = base + j;
        int d = (idx < N) ? deg[idx] : 0;
        s += d;
        v[j] = s;
    }
    tot[threadIdx.x] = s;
    __syncthreads();
    for (int off = 1; off < 256; off <<= 1) {
        int t = (threadIdx.x >= (unsigned)off) ? tot[threadIdx.x - off] : 0;
        __syncthreads();
        tot[threadIdx.x] += t;
        __syncthreads();
    }
    int excl = (threadIdx.x > 0) ? tot[threadIdx.x - 1] : 0;
    for (int j = 0; j < 8; j++) {
        int idx = base + j;
        if (idx < N) tmp[idx] = v[j] + excl;
    }
    if (threadIdx.x == 255) blockSum[blockIdx.x] = tot[255];
}

// --- K2b: finalize row_ptr; chunk offset computed inline (wave reduce) -----
__global__ __launch_bounds__(256) void k_finalize(const int* __restrict__ tmp,
                                                  const int* __restrict__ bsum,
                                                  int N, int* __restrict__ row_ptr) {
    int chunk = (blockIdx.x * 256) >> 11;   // same for whole block
    __shared__ int soff;
    if (threadIdx.x < 64) {
        int v = 0;
        for (int l = threadIdx.x; l < chunk; l += 64) v += bsum[l];
        #pragma unroll
        for (int o = 32; o > 0; o >>= 1) v += __shfl_down(v, o);
        if (threadIdx.x == 0) soff = v;
    }
    __syncthreads();
    int i = blockIdx.x * 256 + threadIdx.x;
    if (i < N) row_ptr[i + 1] = tmp[i] + soff;
    if (i == 0) row_ptr[0] = 0;
}

// --- K3: fill CSR, atomic-free: slot = row_ptr[dst] + rank -----------------
__global__ __launch_bounds__(256) void k_fill(const int* __restrict__ src,
                                              const int* __restrict__ dstA,
                                              const int* __restrict__ et,
                                              const uint8_t* __restrict__ rank,
                                              const int* __restrict__ row_ptr, int E,
                                              int* __restrict__ csr) {
    int e0 = (blockIdx.x * 256 + threadIdx.x) * 4;
    if (e0 + 3 < E) {
        int4 s = *(const int4*)(src + e0);
        int4 d = *(const int4*)(dstA + e0);
        int4 t = *(const int4*)(et + e0);
        uchar4 r = *(const uchar4*)(rank + e0);
        csr[row_ptr[d.x] + r.x] = (s.x << 4) | (t.x & 15);
        csr[row_ptr[d.y] + r.y] = (s.y << 4) | (t.y & 15);
        csr[row_ptr[d.z] + r.z] = (s.z << 4) | (t.z & 15);
        csr[row_ptr[d.w] + r.w] = (s.w << 4) | (t.w & 15);
    } else {
        for (int e = e0; e < E; e++)
            csr[row_ptr[dstA[e]] + rank[e]] = (src[e] << 4) | (et[e] & 15);
    }
}

// gather dword index: src*64 + lane, all in 32-bit off SGPR base
#define G(pp) xb32[((((uint32_t)(pp)) & 0xfffffff0u) << 2) + (uint32_t)lane]

#define CONS(pp, raw) do {                                                \
    uint32_t _r = (raw);                                                  \
    float _x0 = __uint_as_float(_r << 16);                                \
    float _x1 = __uint_as_float(_r & 0xffff0000u);                        \
    const f32x4* _cf = (const f32x4*)&scomp[((pp) & 15) * 8];             \
    f32x4 _c0 = _cf[0];                                                   \
    a[0][0] += _c0.x * _x0; a[0][1] += _c0.x * _x1;                       \
    a[1][0] += _c0.y * _x0; a[1][1] += _c0.y * _x1;                       \
    a[2][0] += _c0.z * _x0; a[2][1] += _c0.z * _x1;                       \
    a[3][0] += _c0.w * _x0; a[3][1] += _c0.w * _x1;                       \
    f32x4 _c1 = _cf[1];                                                   \
    a[4][0] += _c1.x * _x0; a[4][1] += _c1.x * _x1;                       \
    a[5][0] += _c1.y * _x0; a[5][1] += _c1.y * _x1;                       \
    a[6][0] += _c1.z * _x0; a[6][1] += _c1.z * _x1;                       \
    a[7][0] += _c1.w * _x0; a[7][1] += _c1.w * _x1;                       \
} while (0)

// --- K4: FUSED aggregation + MFMA GEMM -------------------------------------
// Block = 16 nodes, 512 thr = 8 waves; wave w aggregates nodes w*2, w*2+1
// (2 ch/lane) with double-buffered 8-edge gather batches (16 loads in flight);
// writes bf16 feat rows to LDS. Phase 2: 16x1152 @ 1152x128 MFMA, wave w owns
// col-tile w.
__global__ __launch_bounds__(512, 8) void k_fused(const __hip_bfloat16* __restrict__ xb,
                                                  const float* __restrict__ comp,
                                                  const int* __restrict__ row_ptr,
                                                  const int* __restrict__ csr,
                                                  const __hip_bfloat16* __restrict__ Wf,
                                                  const float* __restrict__ bias,
                                                  float* __restrict__ out, int M) {
    __shared__ __hip_bfloat16 fl[16][FPAD];
    __shared__ float scomp[128];   // comp [16,8]
    const uint32_t* __restrict__ xb32 = (const uint32_t*)xb;
    int t = threadIdx.x;
    if (t < 128) scomp[t] = comp[t];
    int wid = t >> 6, lane = t & 63;
    int i0 = blockIdx.x * 16;
    __syncthreads();

    // ---- phase 1: aggregate ----
    #pragma unroll 1
    for (int rep = 0; rep < 2; rep++) {
        int lr = wid * 2 + rep;
        int i = i0 + lr;
        float a[8][2];
        #pragma unroll
        for (int b = 0; b < 8; b++) { a[b][0] = 0.f; a[b][1] = 0.f; }
        int s0 = 0, s1 = 0;
        if (i < M) { s0 = row_ptr[i]; s1 = row_ptr[i + 1]; }

        int j = s0;
        // prologue batch (csr is padded by 8 zero entries past E)
        int p0 = csr[j], p1 = csr[j + 1], p2 = csr[j + 2], p3 = csr[j + 3];
        int p4 = csr[j + 4], p5 = csr[j + 5], p6 = csr[j + 6], p7 = csr[j + 7];
        uint32_t w0 = G(p0), w1 = G(p1), w2 = G(p2), w3 = G(p3);
        uint32_t w4 = G(p4), w5 = G(p5), w6 = G(p6), w7 = G(p7);

        #pragma unroll 1
        while (j + 8 < s1) {
            int q0 = csr[j + 8], q1 = csr[j + 9], q2 = csr[j + 10], q3 = csr[j + 11];
            int q4 = csr[j + 12], q5 = csr[j + 13], q6 = csr[j + 14], q7 = csr[j + 15];
            uint32_t v0 = G(q0), v1 = G(q1), v2 = G(q2), v3 = G(q3);
            uint32_t v4 = G(q4), v5 = G(q5), v6 = G(q6), v7 = G(q7);
            CONS(p0, w0); CONS(p1, w1); CONS(p2, w2); CONS(p3, w3);
            CONS(p4, w4); CONS(p5, w5); CONS(p6, w6); CONS(p7, w7);
            p0 = q0; p1 = q1; p2 = q2; p3 = q3;
            p4 = q4; p5 = q5; p6 = q6; p7 = q7;
            w0 = v0; w1 = v1; w2 = v2; w3 = v3;
            w4 = v4; w5 = v5; w6 = v6; w7 = v7;
            j += 8;
        }
        // masked tail (0..8 valid edges)
        CONS(p0, (j + 0 < s1) ? w0 : 0u);
        CONS(p1, (j + 1 < s1) ? w1 : 0u);
        CONS(p2, (j + 2 < s1) ? w2 : 0u);
        CONS(p3, (j + 3 < s1) ? w3 : 0u);
        CONS(p4, (j + 4 < s1) ? w4 : 0u);
        CONS(p5, (j + 5 < s1) ? w5 : 0u);
        CONS(p6, (j + 6 < s1) ? w6 : 0u);
        CONS(p7, (j + 7 < s1) ? w7 : 0u);

        float inv = 1.0f / fmaxf((float)(s1 - s0), 1.0f);
        #pragma unroll
        for (int b = 0; b < 8; b++) {
            __hip_bfloat16 h0 = __float2bfloat16(a[b][0] * inv);
            __hip_bfloat16 h1 = __float2bfloat16(a[b][1] * inv);
            uint32_t pk = ((uint32_t)*(uint16_t*)&h1 << 16) | *(uint16_t*)&h0;
            *(uint32_t*)&fl[lr][b * 128 + lane * 2] = pk;
        }
        uint32_t rr = (i < M) ? xb32[(uint32_t)i * 64u + lane] : 0u;
        *(uint32_t*)&fl[lr][1024 + lane * 2] = rr;
    }
    __syncthreads();

    // ---- phase 2: MFMA; wave wid owns output col-tile wid (cols wid*16..) ----
    int lo = lane & 15, hi = lane >> 4;
    f32x4 acc = (f32x4){0.f, 0.f, 0.f, 0.f};
    const bf16x8* wv = (const bf16x8*)Wf;
    for (int kb = 0; kb < 36; kb++) {
        bf16x8 afrag = *(const bf16x8*)&fl[lo][kb * 32 + hi * 8];
        bf16x8 b = wv[(((kb << 2) + hi) << 7) + wid * 16 + lo];
        acc = __builtin_amdgcn_mfma_f32_16x16x32_bf16(afrag, b, acc, 0, 0, 0);
    }
    float bs = bias[wid * 16 + lo];
    #pragma unroll
    for (int q = 0; q < 4; q++) {
        int row = i0 + hi * 4 + q;   // C/D: col=lane&15, row=(lane>>4)*4+q
        if (row < M)
            out[(size_t)row * 128 + wid * 16 + lo] = acc[q] + bs;
    }
}

extern "C" void kernel_launch(void* const* d_in, const int* in_sizes, int n_in,
                              void* d_out, int out_size, void* d_ws, size_t ws_size,
                              hipStream_t stream) {
    const float* x      = (const float*)d_in[0];   // [N,128]
    const float* weight = (const float*)d_in[1];   // [9,128,128] = [1152,128]
    const float* comp   = (const float*)d_in[2];   // [16,8]
    const float* bias   = (const float*)d_in[3];   // [128]
    const int*   eidx   = (const int*)d_in[4];     // [2,E]
    const int*   etype  = (const int*)d_in[5];     // [E]

    int N = in_sizes[0] / 128;
    int E = in_sizes[5];
    const int* srcA = eidx;
    const int* dstA = eidx + E;

    uint8_t* ws = (uint8_t*)d_ws;
    size_t off = 0;
    auto take = [&](size_t bytes) -> void* {
        void* p = ws + off;
        off = (off + bytes + 255) & ~(size_t)255;
        return p;
    };
    __hip_bfloat16* xb = (__hip_bfloat16*)take((size_t)N * 128 * sizeof(__hip_bfloat16));
    __hip_bfloat16* Wf = (__hip_bfloat16*)take((size_t)1152 * 128 * sizeof(__hip_bfloat16));
    int* deg      = (int*)take((size_t)N * sizeof(int));
    int* tmp      = (int*)take((size_t)N * sizeof(int));
    int* row_ptr  = (int*)take((size_t)(N + 1) * sizeof(int));
    int* bsum     = (int*)take(256 * sizeof(int));
    uint8_t* rank = (uint8_t*)take((size_t)E * sizeof(uint8_t));
    int* csr      = (int*)take((size_t)(E + 8) * sizeof(int));   // +8 pad for batch overrun
    (void)ws_size;

    int n4 = N * 128 / 4;
    int xbB = (n4 + 255) / 256;
    int wpB = (1152 * 128 + 255) / 256;
    int dgB = ((E + 3) / 4 + 255) / 256;
    int nChunks = (N + CHUNK - 1) / CHUNK;

    hipMemsetAsync(deg, 0, (size_t)N * sizeof(int), stream);
    hipMemsetAsync(csr + E, 0, 8 * sizeof(int), stream);
    k_prep<<<xbB + wpB + dgB, 256, 0, stream>>>(x, xb, n4, weight, Wf, dstA, E,
                                                deg, rank, xbB, wpB);
    k_scan_local<<<nChunks, 256, 0, stream>>>(deg, N, tmp, bsum);
    k_finalize<<<(N + 255) / 256, 256, 0, stream>>>(tmp, bsum, N, row_ptr);
    k_fill<<<((E + 3) / 4 + 255) / 256, 256, 0, stream>>>(srcA, dstA, etype, rank,
                                                          row_ptr, E, csr);
    k_fused<<<(N + 15) / 16, 512, 0, stream>>>(xb, comp, row_ptr, csr, Wf, bias,
                                               (float*)d_out, N);
}

// Round 6
// 266.195 us; speedup vs baseline: 6.4105x; 1.2423x over previous
//
#include <hip/hip_runtime.h>
#include <hip/hip_bf16.h>
#include <stdint.h>

// RGCN (basis decomposition, mean agg, root weight + bias)
// Pipeline: prep (xb cast + W frag + deg/rank) -> scan -> finalize ->
// fill (atomic-free) -> FUSED (double-buffered 8-batch gather agg -> LDS ->
// bf16 MFMA GEMM). 512-thr blocks, 8 waves.
// launch_bounds(512,6): VGPR cap ~85 -> no spills (r5's (512,8) cap=64 forced
// VGPR=32 + ~500MB/dispatch scratch traffic), 24 waves/CU = 75% occupancy.

#define CHUNK 2048   // elements per scan block (256 thr x 8)
#define FPAD 1160    // LDS feat row stride in bf16

typedef __attribute__((ext_vector_type(8))) __bf16 bf16x8;
typedef __attribute__((ext_vector_type(4))) float f32x4;

// --- K1: fused prep: xb cast | W fragment pack | deg histogram + rank ------
__global__ __launch_bounds__(256) void k_prep(const float* __restrict__ x,
                                              __hip_bfloat16* __restrict__ xb, int n4,
                                              const float* __restrict__ W,
                                              __hip_bfloat16* __restrict__ Wf,
                                              const int* __restrict__ dst, int E,
                                              int* __restrict__ deg,
                                              uint8_t* __restrict__ rank,
                                              int xbB, int wpB) {
    int b = blockIdx.x;
    if (b < xbB) {
        int i = b * 256 + threadIdx.x;
        if (i < n4) {
            float4 v = ((const float4*)x)[i];
            __hip_bfloat16 h0 = __float2bfloat16(v.x), h1 = __float2bfloat16(v.y);
            __hip_bfloat16 h2 = __float2bfloat16(v.z), h3 = __float2bfloat16(v.w);
            uint32_t p0 = ((uint32_t)*(uint16_t*)&h1 << 16) | *(uint16_t*)&h0;
            uint32_t p1 = ((uint32_t)*(uint16_t*)&h3 << 16) | *(uint16_t*)&h2;
            ((uint2*)xb)[i] = make_uint2(p0, p1);
        }
    } else if (b < xbB + wpB) {
        int idx = (b - xbB) * 256 + threadIdx.x;
        if (idx < 1152 * 128) {
            int k = idx >> 7, n = idx & 127;
            int kb = k >> 5, hi = (k >> 3) & 3, j = k & 7;
            Wf[((((kb << 2) + hi) << 7 | n) << 3) | j] = __float2bfloat16(W[idx]);
        }
    } else {
        int e0 = ((b - xbB - wpB) * 256 + threadIdx.x) * 4;
        if (e0 + 3 < E) {
            int4 d4 = *(const int4*)(dst + e0);
            uchar4 r;
            r.x = (uint8_t)atomicAdd(&deg[d4.x], 1);
            r.y = (uint8_t)atomicAdd(&deg[d4.y], 1);
            r.z = (uint8_t)atomicAdd(&deg[d4.z], 1);
            r.w = (uint8_t)atomicAdd(&deg[d4.w], 1);
            *(uchar4*)(rank + e0) = r;
        } else {
            for (int e = e0; e < E; e++)
                rank[e] = (uint8_t)atomicAdd(&deg[dst[e]], 1);
        }
    }
}

// --- K2a: local inclusive scan over 2048-element chunks ------------------
__global__ __launch_bounds__(256) void k_scan_local(const int* __restrict__ deg, int N,
                                                    int* __restrict__ tmp,
                                                    int* __restrict__ blockSum) {
    __shared__ int tot[256];
    int base = blockIdx.x * CHUNK + threadIdx.x * 8;
    int v[8];
    int s = 0;
    for (int j = 0; j < 8; j++) {
        int idx = base + j;
        int d = (idx < N) ? deg[idx] : 0;
        s += d;
        v[j] = s;
    }
    tot[threadIdx.x] = s;
    __syncthreads();
    for (int off = 1; off < 256; off <<= 1) {
        int t = (threadIdx.x >= (unsigned)off) ? tot[threadIdx.x - off] : 0;
        __syncthreads();
        tot[threadIdx.x] += t;
        __syncthreads();
    }
    int excl = (threadIdx.x > 0) ? tot[threadIdx.x - 1] : 0;
    for (int j = 0; j < 8; j++) {
        int idx = base + j;
        if (idx < N) tmp[idx] = v[j] + excl;
    }
    if (threadIdx.x == 255) blockSum[blockIdx.x] = tot[255];
}

// --- K2b: finalize row_ptr; chunk offset computed inline (wave reduce) -----
__global__ __launch_bounds__(256) void k_finalize(const int* __restrict__ tmp,
                                                  const int* __restrict__ bsum,
                                                  int N, int* __restrict__ row_ptr) {
    int chunk = (blockIdx.x * 256) >> 11;   // same for whole block
    __shared__ int soff;
    if (threadIdx.x < 64) {
        int v = 0;
        for (int l = threadIdx.x; l < chunk; l += 64) v += bsum[l];
        #pragma unroll
        for (int o = 32; o > 0; o >>= 1) v += __shfl_down(v, o);
        if (threadIdx.x == 0) soff = v;
    }
    __syncthreads();
    int i = blockIdx.x * 256 + threadIdx.x;
    if (i < N) row_ptr[i + 1] = tmp[i] + soff;
    if (i == 0) row_ptr[0] = 0;
}

// --- K3: fill CSR, atomic-free: slot = row_ptr[dst] + rank -----------------
__global__ __launch_bounds__(256) void k_fill(const int* __restrict__ src,
                                              const int* __restrict__ dstA,
                                              const int* __restrict__ et,
                                              const uint8_t* __restrict__ rank,
                                              const int* __restrict__ row_ptr, int E,
                                              int* __restrict__ csr) {
    int e0 = (blockIdx.x * 256 + threadIdx.x) * 4;
    if (e0 + 3 < E) {
        int4 s = *(const int4*)(src + e0);
        int4 d = *(const int4*)(dstA + e0);
        int4 t = *(const int4*)(et + e0);
        uchar4 r = *(const uchar4*)(rank + e0);
        csr[row_ptr[d.x] + r.x] = (s.x << 4) | (t.x & 15);
        csr[row_ptr[d.y] + r.y] = (s.y << 4) | (t.y & 15);
        csr[row_ptr[d.z] + r.z] = (s.z << 4) | (t.z & 15);
        csr[row_ptr[d.w] + r.w] = (s.w << 4) | (t.w & 15);
    } else {
        for (int e = e0; e < E; e++)
            csr[row_ptr[dstA[e]] + rank[e]] = (src[e] << 4) | (et[e] & 15);
    }
}

// gather dword index: src*64 + lane, all in 32-bit off SGPR base
#define G(pp) xb32[((((uint32_t)(pp)) & 0xfffffff0u) << 2) + (uint32_t)lane]

#define CONS(pp, raw) do {                                                \
    uint32_t _r = (raw);                                                  \
    float _x0 = __uint_as_float(_r << 16);                                \
    float _x1 = __uint_as_float(_r & 0xffff0000u);                        \
    const f32x4* _cf = (const f32x4*)&scomp[((pp) & 15) * 8];             \
    f32x4 _c0 = _cf[0];                                                   \
    a[0][0] += _c0.x * _x0; a[0][1] += _c0.x * _x1;                       \
    a[1][0] += _c0.y * _x0; a[1][1] += _c0.y * _x1;                       \
    a[2][0] += _c0.z * _x0; a[2][1] += _c0.z * _x1;                       \
    a[3][0] += _c0.w * _x0; a[3][1] += _c0.w * _x1;                       \
    f32x4 _c1 = _cf[1];                                                   \
    a[4][0] += _c1.x * _x0; a[4][1] += _c1.x * _x1;                       \
    a[5][0] += _c1.y * _x0; a[5][1] += _c1.y * _x1;                       \
    a[6][0] += _c1.z * _x0; a[6][1] += _c1.z * _x1;                       \
    a[7][0] += _c1.w * _x0; a[7][1] += _c1.w * _x1;                       \
} while (0)

// --- K4: FUSED aggregation + MFMA GEMM -------------------------------------
// Block = 16 nodes, 512 thr = 8 waves; wave w aggregates nodes w*2, w*2+1
// (2 ch/lane) with double-buffered 8-edge gather batches (16 loads in flight);
// writes bf16 feat rows to LDS. Phase 2: 16x1152 @ 1152x128 MFMA, wave w owns
// col-tile w.
__global__ __launch_bounds__(512, 6) void k_fused(const __hip_bfloat16* __restrict__ xb,
                                                  const float* __restrict__ comp,
                                                  const int* __restrict__ row_ptr,
                                                  const int* __restrict__ csr,
                                                  const __hip_bfloat16* __restrict__ Wf,
                                                  const float* __restrict__ bias,
                                                  float* __restrict__ out, int M) {
    __shared__ __hip_bfloat16 fl[16][FPAD];
    __shared__ float scomp[128];   // comp [16,8]
    const uint32_t* __restrict__ xb32 = (const uint32_t*)xb;
    int t = threadIdx.x;
    if (t < 128) scomp[t] = comp[t];
    int wid = t >> 6, lane = t & 63;
    int i0 = blockIdx.x * 16;
    __syncthreads();

    // ---- phase 1: aggregate ----
    #pragma unroll 1
    for (int rep = 0; rep < 2; rep++) {
        int lr = wid * 2 + rep;
        int i = i0 + lr;
        float a[8][2];
        #pragma unroll
        for (int b = 0; b < 8; b++) { a[b][0] = 0.f; a[b][1] = 0.f; }
        int s0 = 0, s1 = 0;
        if (i < M) { s0 = row_ptr[i]; s1 = row_ptr[i + 1]; }

        int j = s0;
        // prologue batch (csr is padded by 8 zero entries past E)
        int p0 = csr[j], p1 = csr[j + 1], p2 = csr[j + 2], p3 = csr[j + 3];
        int p4 = csr[j + 4], p5 = csr[j + 5], p6 = csr[j + 6], p7 = csr[j + 7];
        uint32_t w0 = G(p0), w1 = G(p1), w2 = G(p2), w3 = G(p3);
        uint32_t w4 = G(p4), w5 = G(p5), w6 = G(p6), w7 = G(p7);

        #pragma unroll 1
        while (j + 8 < s1) {
            int q0 = csr[j + 8], q1 = csr[j + 9], q2 = csr[j + 10], q3 = csr[j + 11];
            int q4 = csr[j + 12], q5 = csr[j + 13], q6 = csr[j + 14], q7 = csr[j + 15];
            uint32_t v0 = G(q0), v1 = G(q1), v2 = G(q2), v3 = G(q3);
            uint32_t v4 = G(q4), v5 = G(q5), v6 = G(q6), v7 = G(q7);
            CONS(p0, w0); CONS(p1, w1); CONS(p2, w2); CONS(p3, w3);
            CONS(p4, w4); CONS(p5, w5); CONS(p6, w6); CONS(p7, w7);
            p0 = q0; p1 = q1; p2 = q2; p3 = q3;
            p4 = q4; p5 = q5; p6 = q6; p7 = q7;
            w0 = v0; w1 = v1; w2 = v2; w3 = v3;
            w4 = v4; w5 = v5; w6 = v6; w7 = v7;
            j += 8;
        }
        // masked tail (0..8 valid edges)
        CONS(p0, (j + 0 < s1) ? w0 : 0u);
        CONS(p1, (j + 1 < s1) ? w1 : 0u);
        CONS(p2, (j + 2 < s1) ? w2 : 0u);
        CONS(p3, (j + 3 < s1) ? w3 : 0u);
        CONS(p4, (j + 4 < s1) ? w4 : 0u);
        CONS(p5, (j + 5 < s1) ? w5 : 0u);
        CONS(p6, (j + 6 < s1) ? w6 : 0u);
        CONS(p7, (j + 7 < s1) ? w7 : 0u);

        float inv = 1.0f / fmaxf((float)(s1 - s0), 1.0f);
        #pragma unroll
        for (int b = 0; b < 8; b++) {
            __hip_bfloat16 h0 = __float2bfloat16(a[b][0] * inv);
            __hip_bfloat16 h1 = __float2bfloat16(a[b][1] * inv);
            uint32_t pk = ((uint32_t)*(uint16_t*)&h1 << 16) | *(uint16_t*)&h0;
            *(uint32_t*)&fl[lr][b * 128 + lane * 2] = pk;
        }
        uint32_t rr = (i < M) ? xb32[(uint32_t)i * 64u + lane] : 0u;
        *(uint32_t*)&fl[lr][1024 + lane * 2] = rr;
    }
    __syncthreads();

    // ---- phase 2: MFMA; wave wid owns output col-tile wid (cols wid*16..) ----
    int lo = lane & 15, hi = lane >> 4;
    f32x4 acc = (f32x4){0.f, 0.f, 0.f, 0.f};
    const bf16x8* wv = (const bf16x8*)Wf;
    for (int kb = 0; kb < 36; kb++) {
        bf16x8 afrag = *(const bf16x8*)&fl[lo][kb * 32 + hi * 8];
        bf16x8 b = wv[(((kb << 2) + hi) << 7) + wid * 16 + lo];
        acc = __builtin_amdgcn_mfma_f32_16x16x32_bf16(afrag, b, acc, 0, 0, 0);
    }
    float bs = bias[wid * 16 + lo];
    #pragma unroll
    for (int q = 0; q < 4; q++) {
        int row = i0 + hi * 4 + q;   // C/D: col=lane&15, row=(lane>>4)*4+q
        if (row < M)
            out[(size_t)row * 128 + wid * 16 + lo] = acc[q] + bs;
    }
}

extern "C" void kernel_launch(void* const* d_in, const int* in_sizes, int n_in,
                              void* d_out, int out_size, void* d_ws, size_t ws_size,
                              hipStream_t stream) {
    const float* x      = (const float*)d_in[0];   // [N,128]
    const float* weight = (const float*)d_in[1];   // [9,128,128] = [1152,128]
    const float* comp   = (const float*)d_in[2];   // [16,8]
    const float* bias   = (const float*)d_in[3];   // [128]
    const int*   eidx   = (const int*)d_in[4];     // [2,E]
    const int*   etype  = (const int*)d_in[5];     // [E]

    int N = in_sizes[0] / 128;
    int E = in_sizes[5];
    const int* srcA = eidx;
    const int* dstA = eidx + E;

    uint8_t* ws = (uint8_t*)d_ws;
    size_t off = 0;
    auto take = [&](size_t bytes) -> void* {
        void* p = ws + off;
        off = (off + bytes + 255) & ~(size_t)255;
        return p;
    };
    __hip_bfloat16* xb = (__hip_bfloat16*)take((size_t)N * 128 * sizeof(__hip_bfloat16));
    __hip_bfloat16* Wf = (__hip_bfloat16*)take((size_t)1152 * 128 * sizeof(__hip_bfloat16));
    int* deg      = (int*)take((size_t)N * sizeof(int));
    int* tmp      = (int*)take((size_t)N * sizeof(int));
    int* row_ptr  = (int*)take((size_t)(N + 1) * sizeof(int));
    int* bsum     = (int*)take(256 * sizeof(int));
    uint8_t* rank = (uint8_t*)take((size_t)E * sizeof(uint8_t));
    int* csr      = (int*)take((size_t)(E + 8) * sizeof(int));   // +8 pad for batch overrun
    (void)ws_size;

    int n4 = N * 128 / 4;
    int xbB = (n4 + 255) / 256;
    int wpB = (1152 * 128 + 255) / 256;
    int dgB = ((E + 3) / 4 + 255) / 256;
    int nChunks = (N + CHUNK - 1) / CHUNK;

    hipMemsetAsync(deg, 0, (size_t)N * sizeof(int), stream);
    hipMemsetAsync(csr + E, 0, 8 * sizeof(int), stream);
    k_prep<<<xbB + wpB + dgB, 256, 0, stream>>>(x, xb, n4, weight, Wf, dstA, E,
                                                deg, rank, xbB, wpB);
    k_scan_local<<<nChunks, 256, 0, stream>>>(deg, N, tmp, bsum);
    k_finalize<<<(N + 255) / 256, 256, 0, stream>>>(tmp, bsum, N, row_ptr);
    k_fill<<<((E + 3) / 4 + 255) / 256, 256, 0, stream>>>(srcA, dstA, etype, rank,
                                                          row_ptr, E, csr);
    k_fused<<<(N + 15) / 16, 512, 0, stream>>>(xb, comp, row_ptr, csr, Wf, bias,
                                               (float*)d_out, N);
}

// Round 7
// 242.835 us; speedup vs baseline: 7.0272x; 1.0962x over previous
//
#include <hip/hip_runtime.h>
#include <hip/hip_bf16.h>
#include <stdint.h>

// RGCN (basis decomposition, mean agg, root weight + bias)
// Pipeline: prep (xb cast + W frag + deg/rank) -> scan -> finalize ->
// fill (atomic-free) -> FUSED (scalar-pipelined 3-stage gather agg -> LDS ->
// bf16 MFMA GEMM).
// Phase 1 control plane is SCALAR: csr entries + comp coeffs are wave-uniform
// (readfirstlane -> s_load), gather address = SGPR base + lane*4. 16 gathers
// in flight per wave, zero LDS in phase 1.

#define CHUNK 2048   // elements per scan block (256 thr x 8)
#define FPAD 1160    // LDS feat row stride in bf16

typedef __attribute__((ext_vector_type(8))) __bf16 bf16x8;
typedef __attribute__((ext_vector_type(4))) float f32x4;

#define RFL(v) __builtin_amdgcn_readfirstlane(v)

// --- K1: fused prep: xb cast | W fragment pack | deg histogram + rank ------
__global__ __launch_bounds__(256) void k_prep(const float* __restrict__ x,
                                              __hip_bfloat16* __restrict__ xb, int n4,
                                              const float* __restrict__ W,
                                              __hip_bfloat16* __restrict__ Wf,
                                              const int* __restrict__ dst, int E,
                                              int* __restrict__ deg,
                                              uint8_t* __restrict__ rank,
                                              int xbB, int wpB) {
    int b = blockIdx.x;
    if (b < xbB) {
        int i = b * 256 + threadIdx.x;
        if (i < n4) {
            float4 v = ((const float4*)x)[i];
            __hip_bfloat16 h0 = __float2bfloat16(v.x), h1 = __float2bfloat16(v.y);
            __hip_bfloat16 h2 = __float2bfloat16(v.z), h3 = __float2bfloat16(v.w);
            uint32_t p0 = ((uint32_t)*(uint16_t*)&h1 << 16) | *(uint16_t*)&h0;
            uint32_t p1 = ((uint32_t)*(uint16_t*)&h3 << 16) | *(uint16_t*)&h2;
            ((uint2*)xb)[i] = make_uint2(p0, p1);
        }
    } else if (b < xbB + wpB) {
        int idx = (b - xbB) * 256 + threadIdx.x;
        if (idx < 1152 * 128) {
            int k = idx >> 7, n = idx & 127;
            int kb = k >> 5, hi = (k >> 3) & 3, j = k & 7;
            Wf[((((kb << 2) + hi) << 7 | n) << 3) | j] = __float2bfloat16(W[idx]);
        }
    } else {
        int e0 = ((b - xbB - wpB) * 256 + threadIdx.x) * 4;
        if (e0 + 3 < E) {
            int4 d4 = *(const int4*)(dst + e0);
            uchar4 r;
            r.x = (uint8_t)atomicAdd(&deg[d4.x], 1);
            r.y = (uint8_t)atomicAdd(&deg[d4.y], 1);
            r.z = (uint8_t)atomicAdd(&deg[d4.z], 1);
            r.w = (uint8_t)atomicAdd(&deg[d4.w], 1);
            *(uchar4*)(rank + e0) = r;
        } else {
            for (int e = e0; e < E; e++)
                rank[e] = (uint8_t)atomicAdd(&deg[dst[e]], 1);
        }
    }
}

// --- K2a: local inclusive scan over 2048-element chunks ------------------
__global__ __launch_bounds__(256) void k_scan_local(const int* __restrict__ deg, int N,
                                                    int* __restrict__ tmp,
                                                    int* __restrict__ blockSum) {
    __shared__ int tot[256];
    int base = blockIdx.x * CHUNK + threadIdx.x * 8;
    int v[8];
    int s = 0;
    for (int j = 0; j < 8; j++) {
        int idx = base + j;
        int d = (idx < N) ? deg[idx] : 0;
        s += d;
        v[j] = s;
    }
    tot[threadIdx.x] = s;
    __syncthreads();
    for (int off = 1; off < 256; off <<= 1) {
        int t = (threadIdx.x >= (unsigned)off) ? tot[threadIdx.x - off] : 0;
        __syncthreads();
        tot[threadIdx.x] += t;
        __syncthreads();
    }
    int excl = (threadIdx.x > 0) ? tot[threadIdx.x - 1] : 0;
    for (int j = 0; j < 8; j++) {
        int idx = base + j;
        if (idx < N) tmp[idx] = v[j] + excl;
    }
    if (threadIdx.x == 255) blockSum[blockIdx.x] = tot[255];
}

// --- K2b: finalize row_ptr; chunk offset computed inline (wave reduce) -----
__global__ __launch_bounds__(256) void k_finalize(const int* __restrict__ tmp,
                                                  const int* __restrict__ bsum,
                                                  int N, int* __restrict__ row_ptr) {
    int chunk = (blockIdx.x * 256) >> 11;   // same for whole block
    __shared__ int soff;
    if (threadIdx.x < 64) {
        int v = 0;
        for (int l = threadIdx.x; l < chunk; l += 64) v += bsum[l];
        #pragma unroll
        for (int o = 32; o > 0; o >>= 1) v += __shfl_down(v, o);
        if (threadIdx.x == 0) soff = v;
    }
    __syncthreads();
    int i = blockIdx.x * 256 + threadIdx.x;
    if (i < N) row_ptr[i + 1] = tmp[i] + soff;
    if (i == 0) row_ptr[0] = 0;
}

// --- K3: fill CSR, atomic-free: slot = row_ptr[dst] + rank -----------------
__global__ __launch_bounds__(256) void k_fill(const int* __restrict__ src,
                                              const int* __restrict__ dstA,
                                              const int* __restrict__ et,
                                              const uint8_t* __restrict__ rank,
                                              const int* __restrict__ row_ptr, int E,
                                              int* __restrict__ csr) {
    int e0 = (blockIdx.x * 256 + threadIdx.x) * 4;
    if (e0 + 3 < E) {
        int4 s = *(const int4*)(src + e0);
        int4 d = *(const int4*)(dstA + e0);
        int4 t = *(const int4*)(et + e0);
        uchar4 r = *(const uchar4*)(rank + e0);
        csr[row_ptr[d.x] + r.x] = (s.x << 4) | (t.x & 15);
        csr[row_ptr[d.y] + r.y] = (s.y << 4) | (t.y & 15);
        csr[row_ptr[d.z] + r.z] = (s.z << 4) | (t.z & 15);
        csr[row_ptr[d.w] + r.w] = (s.w << 4) | (t.w & 15);
    } else {
        for (int e = e0; e < E; e++)
            csr[row_ptr[dstA[e]] + rank[e]] = (src[e] << 4) | (et[e] & 15);
    }
}

// uniform gather: pp is wave-uniform (SGPR); address = SGPR base + lane*4
#define GATH(pp) xb32[(uint32_t)((pp) >> 4) * 64u + (uint32_t)lane]

// consume one edge: cf loads are uniform (scalar), FMAs take SGPR operand
#define CONS1(pp, raw) do {                                               \
    uint32_t _r = (raw);                                                  \
    float _x0 = __uint_as_float(_r << 16);                                \
    float _x1 = __uint_as_float(_r & 0xffff0000u);                        \
    const float* _cf = comp + ((pp) & 15) * 8;                            \
    a[0][0] += _cf[0] * _x0; a[0][1] += _cf[0] * _x1;                     \
    a[1][0] += _cf[1] * _x0; a[1][1] += _cf[1] * _x1;                     \
    a[2][0] += _cf[2] * _x0; a[2][1] += _cf[2] * _x1;                     \
    a[3][0] += _cf[3] * _x0; a[3][1] += _cf[3] * _x1;                     \
    a[4][0] += _cf[4] * _x0; a[4][1] += _cf[4] * _x1;                     \
    a[5][0] += _cf[5] * _x0; a[5][1] += _cf[5] * _x1;                     \
    a[6][0] += _cf[6] * _x0; a[6][1] += _cf[6] * _x1;                     \
    a[7][0] += _cf[7] * _x0; a[7][1] += _cf[7] * _x1;                     \
} while (0)

// --- K4: FUSED aggregation + MFMA GEMM -------------------------------------
// Block = 16 nodes, 512 thr = 8 waves; wave w aggregates nodes w*2, w*2+1
// (2 ch/lane). 3-stage pipeline: 16 uniform-addressed gathers in flight;
// csr/comp on the scalar pipe. Phase 2: 16x1152 @ 1152x128 MFMA, wave w owns
// col-tile w.
__global__ __launch_bounds__(512, 6) void k_fused(const __hip_bfloat16* __restrict__ xb,
                                                  const float* __restrict__ comp,
                                                  const int* __restrict__ row_ptr,
                                                  const int* __restrict__ csr,
                                                  const __hip_bfloat16* __restrict__ Wf,
                                                  const float* __restrict__ bias,
                                                  float* __restrict__ out, int M) {
    __shared__ __hip_bfloat16 fl[16][FPAD];
    const uint32_t* __restrict__ xb32 = (const uint32_t*)xb;
    int t = threadIdx.x;
    int wid = t >> 6, lane = t & 63;
    int i0 = blockIdx.x * 16;

    // ---- phase 1: aggregate (no LDS, scalar control plane) ----
    #pragma unroll 1
    for (int rep = 0; rep < 2; rep++) {
        int lr = wid * 2 + rep;
        int iu = RFL(i0 + lr);          // uniform node id
        float a[8][2];
        #pragma unroll
        for (int b = 0; b < 8; b++) { a[b][0] = 0.f; a[b][1] = 0.f; }
        int s0 = 0, s1 = 0;
        if (iu < M) {                    // uniform branch
            s0 = RFL(row_ptr[iu]);
            s1 = RFL(row_ptr[iu + 1]);
        }

        int jj = s0;
        // stage 0 (consuming) + stage 1 (in flight); csr padded by 24
        int p0 = RFL(csr[jj]),     p1 = RFL(csr[jj + 1]);
        int p2 = RFL(csr[jj + 2]), p3 = RFL(csr[jj + 3]);
        int p4 = RFL(csr[jj + 4]), p5 = RFL(csr[jj + 5]);
        int p6 = RFL(csr[jj + 6]), p7 = RFL(csr[jj + 7]);
        uint32_t w0 = GATH(p0), w1 = GATH(p1), w2 = GATH(p2), w3 = GATH(p3);
        uint32_t w4 = GATH(p4), w5 = GATH(p5), w6 = GATH(p6), w7 = GATH(p7);
        int q0 = RFL(csr[jj + 8]),  q1 = RFL(csr[jj + 9]);
        int q2 = RFL(csr[jj + 10]), q3 = RFL(csr[jj + 11]);
        int q4 = RFL(csr[jj + 12]), q5 = RFL(csr[jj + 13]);
        int q6 = RFL(csr[jj + 14]), q7 = RFL(csr[jj + 15]);
        uint32_t v0 = GATH(q0), v1 = GATH(q1), v2 = GATH(q2), v3 = GATH(q3);
        uint32_t v4 = GATH(q4), v5 = GATH(q5), v6 = GATH(q6), v7 = GATH(q7);

        #pragma unroll 1
        while (jj + 16 < s1) {
            // stage 2: issue next batch (scalar csr + uniform-base gathers)
            int r0 = RFL(csr[jj + 16]), r1 = RFL(csr[jj + 17]);
            int r2 = RFL(csr[jj + 18]), r3 = RFL(csr[jj + 19]);
            int r4 = RFL(csr[jj + 20]), r5 = RFL(csr[jj + 21]);
            int r6 = RFL(csr[jj + 22]), r7 = RFL(csr[jj + 23]);
            uint32_t u0 = GATH(r0), u1 = GATH(r1), u2 = GATH(r2), u3 = GATH(r3);
            uint32_t u4 = GATH(r4), u5 = GATH(r5), u6 = GATH(r6), u7 = GATH(r7);
            CONS1(p0, w0); CONS1(p1, w1); CONS1(p2, w2); CONS1(p3, w3);
            CONS1(p4, w4); CONS1(p5, w5); CONS1(p6, w6); CONS1(p7, w7);
            p0 = q0; p1 = q1; p2 = q2; p3 = q3;
            p4 = q4; p5 = q5; p6 = q6; p7 = q7;
            w0 = v0; w1 = v1; w2 = v2; w3 = v3;
            w4 = v4; w5 = v5; w6 = v6; w7 = v7;
            q0 = r0; q1 = r1; q2 = r2; q3 = r3;
            q4 = r4; q5 = r5; q6 = r6; q7 = r7;
            v0 = u0; v1 = u1; v2 = u2; v3 = u3;
            v4 = u4; v5 = u5; v6 = u6; v7 = u7;
            jj += 8;
        }
        // masked tails (uniform conditions)
        CONS1(p0, (jj + 0 < s1) ? w0 : 0u);
        CONS1(p1, (jj + 1 < s1) ? w1 : 0u);
        CONS1(p2, (jj + 2 < s1) ? w2 : 0u);
        CONS1(p3, (jj + 3 < s1) ? w3 : 0u);
        CONS1(p4, (jj + 4 < s1) ? w4 : 0u);
        CONS1(p5, (jj + 5 < s1) ? w5 : 0u);
        CONS1(p6, (jj + 6 < s1) ? w6 : 0u);
        CONS1(p7, (jj + 7 < s1) ? w7 : 0u);
        CONS1(q0, (jj + 8 < s1) ? v0 : 0u);
        CONS1(q1, (jj + 9 < s1) ? v1 : 0u);
        CONS1(q2, (jj + 10 < s1) ? v2 : 0u);
        CONS1(q3, (jj + 11 < s1) ? v3 : 0u);
        CONS1(q4, (jj + 12 < s1) ? v4 : 0u);
        CONS1(q5, (jj + 13 < s1) ? v5 : 0u);
        CONS1(q6, (jj + 14 < s1) ? v6 : 0u);
        CONS1(q7, (jj + 15 < s1) ? v7 : 0u);

        float inv = 1.0f / fmaxf((float)(s1 - s0), 1.0f);
        #pragma unroll
        for (int b = 0; b < 8; b++) {
            __hip_bfloat16 h0 = __float2bfloat16(a[b][0] * inv);
            __hip_bfloat16 h1 = __float2bfloat16(a[b][1] * inv);
            uint32_t pk = ((uint32_t)*(uint16_t*)&h1 << 16) | *(uint16_t*)&h0;
            *(uint32_t*)&fl[lr][b * 128 + lane * 2] = pk;
        }
        uint32_t rr = (iu < M) ? xb32[(uint32_t)iu * 64u + lane] : 0u;
        *(uint32_t*)&fl[lr][1024 + lane * 2] = rr;
    }
    __syncthreads();

    // ---- phase 2: MFMA; wave wid owns output col-tile wid (cols wid*16..) ----
    int lo = lane & 15, hi = lane >> 4;
    f32x4 acc = (f32x4){0.f, 0.f, 0.f, 0.f};
    const bf16x8* wv = (const bf16x8*)Wf;
    for (int kb = 0; kb < 36; kb++) {
        bf16x8 afrag = *(const bf16x8*)&fl[lo][kb * 32 + hi * 8];
        bf16x8 b = wv[(((kb << 2) + hi) << 7) + wid * 16 + lo];
        acc = __builtin_amdgcn_mfma_f32_16x16x32_bf16(afrag, b, acc, 0, 0, 0);
    }
    float bs = bias[wid * 16 + lo];
    #pragma unroll
    for (int q = 0; q < 4; q++) {
        int row = i0 + hi * 4 + q;   // C/D: col=lane&15, row=(lane>>4)*4+q
        if (row < M)
            out[(size_t)row * 128 + wid * 16 + lo] = acc[q] + bs;
    }
}

extern "C" void kernel_launch(void* const* d_in, const int* in_sizes, int n_in,
                              void* d_out, int out_size, void* d_ws, size_t ws_size,
                              hipStream_t stream) {
    const float* x      = (const float*)d_in[0];   // [N,128]
    const float* weight = (const float*)d_in[1];   // [9,128,128] = [1152,128]
    const float* comp   = (const float*)d_in[2];   // [16,8]
    const float* bias   = (const float*)d_in[3];   // [128]
    const int*   eidx   = (const int*)d_in[4];     // [2,E]
    const int*   etype  = (const int*)d_in[5];     // [E]

    int N = in_sizes[0] / 128;
    int E = in_sizes[5];
    const int* srcA = eidx;
    const int* dstA = eidx + E;

    uint8_t* ws = (uint8_t*)d_ws;
    size_t off = 0;
    auto take = [&](size_t bytes) -> void* {
        void* p = ws + off;
        off = (off + bytes + 255) & ~(size_t)255;
        return p;
    };
    __hip_bfloat16* xb = (__hip_bfloat16*)take((size_t)N * 128 * sizeof(__hip_bfloat16));
    __hip_bfloat16* Wf = (__hip_bfloat16*)take((size_t)1152 * 128 * sizeof(__hip_bfloat16));
    int* deg      = (int*)take((size_t)N * sizeof(int));
    int* tmp      = (int*)take((size_t)N * sizeof(int));
    int* row_ptr  = (int*)take((size_t)(N + 1) * sizeof(int));
    int* bsum     = (int*)take(256 * sizeof(int));
    uint8_t* rank = (uint8_t*)take((size_t)E * sizeof(uint8_t));
    int* csr      = (int*)take((size_t)(E + 24) * sizeof(int));  // +24 pad for 3-stage overrun
    (void)ws_size;

    int n4 = N * 128 / 4;
    int xbB = (n4 + 255) / 256;
    int wpB = (1152 * 128 + 255) / 256;
    int dgB = ((E + 3) / 4 + 255) / 256;
    int nChunks = (N + CHUNK - 1) / CHUNK;

    hipMemsetAsync(deg, 0, (size_t)N * sizeof(int), stream);
    hipMemsetAsync(csr + E, 0, 24 * sizeof(int), stream);
    k_prep<<<xbB + wpB + dgB, 256, 0, stream>>>(x, xb, n4, weight, Wf, dstA, E,
                                                deg, rank, xbB, wpB);
    k_scan_local<<<nChunks, 256, 0, stream>>>(deg, N, tmp, bsum);
    k_finalize<<<(N + 255) / 256, 256, 0, stream>>>(tmp, bsum, N, row_ptr);
    k_fill<<<((E + 3) / 4 + 255) / 256, 256, 0, stream>>>(srcA, dstA, etype, rank,
                                                          row_ptr, E, csr);
    k_fused<<<(N + 15) / 16, 512, 0, stream>>>(xb, comp, row_ptr, csr, Wf, bias,
                                               (float*)d_out, N);
}

// Round 8
// 202.722 us; speedup vs baseline: 8.4177x; 1.1979x over previous
//
#include <hip/hip_runtime.h>
#include <hip/hip_bf16.h>
#include <stdint.h>

// RGCN (basis decomposition, mean agg, root weight + bias)
// Pipeline: prep (xb cast + W frag + bucket histogram) -> bucket scan ->
// bucket scatter -> per-bucket counting sort (csr + row_ptr) ->
// FUSED (scalar-pipelined gather agg -> LDS -> bf16 MFMA GEMM).
// CSR build is a 2-level bucket sort: 76K global atomics instead of 1.6M,
// all global reads/writes coalesced or bucket-local.

#define FPAD 1160    // LDS feat row stride in bf16
#define SCAT_CH 8192 // edges per k_bscatter block

typedef __attribute__((ext_vector_type(8))) __bf16 bf16x8;
typedef __attribute__((ext_vector_type(4))) float f32x4;

#define RFL(v) __builtin_amdgcn_readfirstlane(v)

// --- K1: fused prep: xb cast | W fragment pack | bucket histogram ----------
__global__ __launch_bounds__(256) void k_prep(const float* __restrict__ x,
                                              __hip_bfloat16* __restrict__ xb, int n4,
                                              const float* __restrict__ W,
                                              __hip_bfloat16* __restrict__ Wf,
                                              const int* __restrict__ dst, int E,
                                              int* __restrict__ bcnt, int NB,
                                              int xbB, int wpB, int hbB) {
    extern __shared__ int sc[];
    int b = blockIdx.x;
    if (b < xbB) {
        int i = b * 256 + threadIdx.x;
        if (i < n4) {
            float4 v = ((const float4*)x)[i];
            __hip_bfloat16 h0 = __float2bfloat16(v.x), h1 = __float2bfloat16(v.y);
            __hip_bfloat16 h2 = __float2bfloat16(v.z), h3 = __float2bfloat16(v.w);
            uint32_t p0 = ((uint32_t)*(uint16_t*)&h1 << 16) | *(uint16_t*)&h0;
            uint32_t p1 = ((uint32_t)*(uint16_t*)&h3 << 16) | *(uint16_t*)&h2;
            ((uint2*)xb)[i] = make_uint2(p0, p1);
        }
    } else if (b < xbB + wpB) {
        int idx = (b - xbB) * 256 + threadIdx.x;
        if (idx < 1152 * 128) {
            int k = idx >> 7, n = idx & 127;
            int kb = k >> 5, hi = (k >> 3) & 3, j = k & 7;
            Wf[((((kb << 2) + hi) << 7 | n) << 3) | j] = __float2bfloat16(W[idx]);
        }
    } else {
        // bucket histogram: LDS pre-aggregate, then one atomic per nonzero bucket
        for (int i = threadIdx.x; i < NB; i += 256) sc[i] = 0;
        __syncthreads();
        int hb = b - xbB - wpB;
        int stride = hbB * 256;
        for (int e = hb * 256 + threadIdx.x; e < E; e += stride)
            atomicAdd(&sc[dst[e] >> 7], 1);
        __syncthreads();
        for (int i = threadIdx.x; i < NB; i += 256) {
            int c = sc[i];
            if (c) atomicAdd(&bcnt[i], c);
        }
    }
}

// --- K2: scan bucket counts -> base[NB+1], cursor copy, row_ptr[N]=E -------
// single block, 1024 threads; requires NB <= 1024 (N=100k -> NB=782)
__global__ __launch_bounds__(1024) void k_bscan(const int* __restrict__ bcnt, int NB,
                                                int E, int N,
                                                int* __restrict__ base,
                                                int* __restrict__ cursor,
                                                int* __restrict__ row_ptr) {
    __shared__ int s[1024];
    int t = threadIdx.x;
    int v = (t < NB) ? bcnt[t] : 0;
    s[t] = v;
    __syncthreads();
    for (int off = 1; off < 1024; off <<= 1) {
        int u = (t >= off) ? s[t - off] : 0;
        __syncthreads();
        s[t] += u;
        __syncthreads();
    }
    int excl = (t > 0) ? s[t - 1] : 0;
    if (t < NB) { base[t] = excl; cursor[t] = excl; }
    if (t == 0) { base[NB] = E; row_ptr[N] = E; }
}

// --- K3: scatter edges into bucket-contiguous records ----------------------
// record = (src<<11) | (dst&127)<<4 | et   (src<2^17, 7-bit local dst, 4-bit et)
__global__ __launch_bounds__(256) void k_bscatter(const int* __restrict__ src,
                                                  const int* __restrict__ dst,
                                                  const int* __restrict__ et,
                                                  int E, int NB,
                                                  int* __restrict__ cursor,
                                                  int* __restrict__ brec) {
    extern __shared__ int sm[];   // [NB] cnt, [NB] gbase
    int* cnt = sm;
    int* gb  = sm + NB;
    for (int i = threadIdx.x; i < NB; i += 256) cnt[i] = 0;
    __syncthreads();
    int e0 = blockIdx.x * SCAT_CH;
    int e1 = min(e0 + SCAT_CH, E);
    for (int e = e0 + threadIdx.x; e < e1; e += 256)
        atomicAdd(&cnt[dst[e] >> 7], 1);
    __syncthreads();
    for (int i = threadIdx.x; i < NB; i += 256) {
        int c = cnt[i];
        gb[i] = c ? atomicAdd(&cursor[i], c) : 0;
    }
    __syncthreads();
    for (int i = threadIdx.x; i < NB; i += 256) cnt[i] = 0;
    __syncthreads();
    for (int e = e0 + threadIdx.x; e < e1; e += 256) {
        int d = dst[e];
        int bk = d >> 7;
        int off = atomicAdd(&cnt[bk], 1);
        brec[gb[bk] + off] = (src[e] << 11) | ((d & 127) << 4) | (et[e] & 15);
    }
}

// --- K4: per-bucket counting sort -> csr + row_ptr -------------------------
__global__ __launch_bounds__(256) void k_bsort(const int* __restrict__ brec,
                                               const int* __restrict__ base,
                                               int N,
                                               int* __restrict__ row_ptr,
                                               int* __restrict__ csr) {
    __shared__ int cnt[128], st[128];
    int b = blockIdx.x;
    int s0 = base[b], s1 = base[b + 1];
    int t = threadIdx.x;
    if (t < 128) cnt[t] = 0;
    __syncthreads();
    for (int i = s0 + t; i < s1; i += 256)
        atomicAdd(&cnt[(brec[i] >> 4) & 127], 1);
    __syncthreads();
    if (t < 128) st[t] = cnt[t];
    __syncthreads();
    for (int off = 1; off < 128; off <<= 1) {
        int u = 0;
        if (t < 128 && t >= off) u = st[t - off];
        __syncthreads();
        if (t < 128) st[t] += u;
        __syncthreads();
    }
    if (t < 128) {
        int excl = st[t] - cnt[t];
        int d = b * 128 + t;
        if (d < N) row_ptr[d] = s0 + excl;
        cnt[t] = excl;   // reuse as running cursor
    }
    __syncthreads();
    for (int i = s0 + t; i < s1; i += 256) {
        int r = brec[i];
        int d7 = (r >> 4) & 127;
        int off = atomicAdd(&cnt[d7], 1);
        csr[s0 + off] = ((r >> 11) << 4) | (r & 15);
    }
}

// uniform gather: pp is wave-uniform (SGPR); address = SGPR base + lane*4
#define GATH(pp) xb32[(uint32_t)((pp) >> 4) * 64u + (uint32_t)lane]

// consume one edge: cf loads are uniform (scalar), FMAs take SGPR operand
#define CONS1(pp, raw) do {                                               \
    uint32_t _r = (raw);                                                  \
    float _x0 = __uint_as_float(_r << 16);                                \
    float _x1 = __uint_as_float(_r & 0xffff0000u);                        \
    const float* _cf = comp + ((pp) & 15) * 8;                            \
    a[0][0] += _cf[0] * _x0; a[0][1] += _cf[0] * _x1;                     \
    a[1][0] += _cf[1] * _x0; a[1][1] += _cf[1] * _x1;                     \
    a[2][0] += _cf[2] * _x0; a[2][1] += _cf[2] * _x1;                     \
    a[3][0] += _cf[3] * _x0; a[3][1] += _cf[3] * _x1;                     \
    a[4][0] += _cf[4] * _x0; a[4][1] += _cf[4] * _x1;                     \
    a[5][0] += _cf[5] * _x0; a[5][1] += _cf[5] * _x1;                     \
    a[6][0] += _cf[6] * _x0; a[6][1] += _cf[6] * _x1;                     \
    a[7][0] += _cf[7] * _x0; a[7][1] += _cf[7] * _x1;                     \
} while (0)

// --- K5: FUSED aggregation + MFMA GEMM -------------------------------------
// Block = 16 nodes, 512 thr = 8 waves; wave w aggregates nodes w*2, w*2+1
// (2 ch/lane). 3-stage pipeline: 16 uniform-addressed gathers in flight;
// csr/comp on the scalar pipe. Phase 2: 16x1152 @ 1152x128 MFMA with explicit
// next-(A,B) prefetch; wave w owns col-tile w.
__global__ __launch_bounds__(512, 6) void k_fused(const __hip_bfloat16* __restrict__ xb,
                                                  const float* __restrict__ comp,
                                                  const int* __restrict__ row_ptr,
                                                  const int* __restrict__ csr,
                                                  const __hip_bfloat16* __restrict__ Wf,
                                                  const float* __restrict__ bias,
                                                  float* __restrict__ out, int M) {
    __shared__ __hip_bfloat16 fl[16][FPAD];
    const uint32_t* __restrict__ xb32 = (const uint32_t*)xb;
    int t = threadIdx.x;
    int wid = t >> 6, lane = t & 63;
    int i0 = blockIdx.x * 16;

    // ---- phase 1: aggregate (no LDS, scalar control plane) ----
    #pragma unroll 1
    for (int rep = 0; rep < 2; rep++) {
        int lr = wid * 2 + rep;
        int iu = RFL(i0 + lr);          // uniform node id
        float a[8][2];
        #pragma unroll
        for (int b = 0; b < 8; b++) { a[b][0] = 0.f; a[b][1] = 0.f; }
        int s0 = 0, s1 = 0;
        if (iu < M) {                    // uniform branch
            s0 = RFL(row_ptr[iu]);
            s1 = RFL(row_ptr[iu + 1]);
        }

        int jj = s0;
        // stage 0 (consuming) + stage 1 (in flight); csr padded by 24
        int p0 = RFL(csr[jj]),     p1 = RFL(csr[jj + 1]);
        int p2 = RFL(csr[jj + 2]), p3 = RFL(csr[jj + 3]);
        int p4 = RFL(csr[jj + 4]), p5 = RFL(csr[jj + 5]);
        int p6 = RFL(csr[jj + 6]), p7 = RFL(csr[jj + 7]);
        uint32_t w0 = GATH(p0), w1 = GATH(p1), w2 = GATH(p2), w3 = GATH(p3);
        uint32_t w4 = GATH(p4), w5 = GATH(p5), w6 = GATH(p6), w7 = GATH(p7);
        int q0 = RFL(csr[jj + 8]),  q1 = RFL(csr[jj + 9]);
        int q2 = RFL(csr[jj + 10]), q3 = RFL(csr[jj + 11]);
        int q4 = RFL(csr[jj + 12]), q5 = RFL(csr[jj + 13]);
        int q6 = RFL(csr[jj + 14]), q7 = RFL(csr[jj + 15]);
        uint32_t v0 = GATH(q0), v1 = GATH(q1), v2 = GATH(q2), v3 = GATH(q3);
        uint32_t v4 = GATH(q4), v5 = GATH(q5), v6 = GATH(q6), v7 = GATH(q7);

        #pragma unroll 1
        while (jj + 16 < s1) {
            // stage 2: issue next batch (scalar csr + uniform-base gathers)
            int r0 = RFL(csr[jj + 16]), r1 = RFL(csr[jj + 17]);
            int r2 = RFL(csr[jj + 18]), r3 = RFL(csr[jj + 19]);
            int r4 = RFL(csr[jj + 20]), r5 = RFL(csr[jj + 21]);
            int r6 = RFL(csr[jj + 22]), r7 = RFL(csr[jj + 23]);
            uint32_t u0 = GATH(r0), u1 = GATH(r1), u2 = GATH(r2), u3 = GATH(r3);
            uint32_t u4 = GATH(r4), u5 = GATH(r5), u6 = GATH(r6), u7 = GATH(r7);
            CONS1(p0, w0); CONS1(p1, w1); CONS1(p2, w2); CONS1(p3, w3);
            CONS1(p4, w4); CONS1(p5, w5); CONS1(p6, w6); CONS1(p7, w7);
            p0 = q0; p1 = q1; p2 = q2; p3 = q3;
            p4 = q4; p5 = q5; p6 = q6; p7 = q7;
            w0 = v0; w1 = v1; w2 = v2; w3 = v3;
            w4 = v4; w5 = v5; w6 = v6; w7 = v7;
            q0 = r0; q1 = r1; q2 = r2; q3 = r3;
            q4 = r4; q5 = r5; q6 = r6; q7 = r7;
            v0 = u0; v1 = u1; v2 = u2; v3 = u3;
            v4 = u4; v5 = u5; v6 = u6; v7 = u7;
            jj += 8;
        }
        // masked tails (uniform conditions)
        CONS1(p0, (jj + 0 < s1) ? w0 : 0u);
        CONS1(p1, (jj + 1 < s1) ? w1 : 0u);
        CONS1(p2, (jj + 2 < s1) ? w2 : 0u);
        CONS1(p3, (jj + 3 < s1) ? w3 : 0u);
        CONS1(p4, (jj + 4 < s1) ? w4 : 0u);
        CONS1(p5, (jj + 5 < s1) ? w5 : 0u);
        CONS1(p6, (jj + 6 < s1) ? w6 : 0u);
        CONS1(p7, (jj + 7 < s1) ? w7 : 0u);
        CONS1(q0, (jj + 8 < s1) ? v0 : 0u);
        CONS1(q1, (jj + 9 < s1) ? v1 : 0u);
        CONS1(q2, (jj + 10 < s1) ? v2 : 0u);
        CONS1(q3, (jj + 11 < s1) ? v3 : 0u);
        CONS1(q4, (jj + 12 < s1) ? v4 : 0u);
        CONS1(q5, (jj + 13 < s1) ? v5 : 0u);
        CONS1(q6, (jj + 14 < s1) ? v6 : 0u);
        CONS1(q7, (jj + 15 < s1) ? v7 : 0u);

        float inv = 1.0f / fmaxf((float)(s1 - s0), 1.0f);
        #pragma unroll
        for (int b = 0; b < 8; b++) {
            __hip_bfloat16 h0 = __float2bfloat16(a[b][0] * inv);
            __hip_bfloat16 h1 = __float2bfloat16(a[b][1] * inv);
            uint32_t pk = ((uint32_t)*(uint16_t*)&h1 << 16) | *(uint16_t*)&h0;
            *(uint32_t*)&fl[lr][b * 128 + lane * 2] = pk;
        }
        uint32_t rr = (iu < M) ? xb32[(uint32_t)iu * 64u + lane] : 0u;
        *(uint32_t*)&fl[lr][1024 + lane * 2] = rr;
    }
    __syncthreads();

    // ---- phase 2: MFMA, 2-stage prefetch; wave wid owns col-tile wid ----
    int lo = lane & 15, hi = lane >> 4;
    f32x4 acc = (f32x4){0.f, 0.f, 0.f, 0.f};
    const bf16x8* wv = (const bf16x8*)Wf;
    bf16x8 aC = *(const bf16x8*)&fl[lo][hi * 8];
    bf16x8 bC = wv[(hi << 7) + wid * 16 + lo];
    #pragma unroll 4
    for (int kb = 0; kb < 36; kb++) {
        int kn = (kb < 35) ? kb + 1 : 35;
        bf16x8 aN = *(const bf16x8*)&fl[lo][kn * 32 + hi * 8];
        bf16x8 bN = wv[(((kn << 2) + hi) << 7) + wid * 16 + lo];
        acc = __builtin_amdgcn_mfma_f32_16x16x32_bf16(aC, bC, acc, 0, 0, 0);
        aC = aN; bC = bN;
    }
    float bs = bias[wid * 16 + lo];
    #pragma unroll
    for (int q = 0; q < 4; q++) {
        int row = i0 + hi * 4 + q;   // C/D: col=lane&15, row=(lane>>4)*4+q
        if (row < M)
            out[(size_t)row * 128 + wid * 16 + lo] = acc[q] + bs;
    }
}

extern "C" void kernel_launch(void* const* d_in, const int* in_sizes, int n_in,
                              void* d_out, int out_size, void* d_ws, size_t ws_size,
                              hipStream_t stream) {
    const float* x      = (const float*)d_in[0];   // [N,128]
    const float* weight = (const float*)d_in[1];   // [9,128,128] = [1152,128]
    const float* comp   = (const float*)d_in[2];   // [16,8]
    const float* bias   = (const float*)d_in[3];   // [128]
    const int*   eidx   = (const int*)d_in[4];     // [2,E]
    const int*   etype  = (const int*)d_in[5];     // [E]

    int N = in_sizes[0] / 128;
    int E = in_sizes[5];
    const int* srcA = eidx;
    const int* dstA = eidx + E;
    int NB = (N + 127) >> 7;                       // buckets of 128 dsts (<=1024)

    uint8_t* ws = (uint8_t*)d_ws;
    size_t off = 0;
    auto take = [&](size_t bytes) -> void* {
        void* p = ws + off;
        off = (off + bytes + 255) & ~(size_t)255;
        return p;
    };
    __hip_bfloat16* xb = (__hip_bfloat16*)take((size_t)N * 128 * sizeof(__hip_bfloat16));
    __hip_bfloat16* Wf = (__hip_bfloat16*)take((size_t)1152 * 128 * sizeof(__hip_bfloat16));
    int* row_ptr = (int*)take((size_t)(N + 1) * sizeof(int));
    int* bcnt    = (int*)take((size_t)NB * sizeof(int));
    int* base    = (int*)take((size_t)(NB + 1) * sizeof(int));
    int* cursor  = (int*)take((size_t)NB * sizeof(int));
    int* brec    = (int*)take((size_t)E * sizeof(int));
    int* csr     = (int*)take((size_t)(E + 24) * sizeof(int));  // +24 pipeline pad
    (void)ws_size;

    int n4 = N * 128 / 4;
    int xbB = (n4 + 255) / 256;
    int wpB = (1152 * 128 + 255) / 256;
    int hbB = 256;                                  // histogram blocks
    int scB = (E + SCAT_CH - 1) / SCAT_CH;

    hipMemsetAsync(bcnt, 0, (size_t)NB * sizeof(int), stream);
    hipMemsetAsync(csr + E, 0, 24 * sizeof(int), stream);
    k_prep<<<xbB + wpB + hbB, 256, NB * sizeof(int), stream>>>(
        x, xb, n4, weight, Wf, dstA, E, bcnt, NB, xbB, wpB, hbB);
    k_bscan<<<1, 1024, 0, stream>>>(bcnt, NB, E, N, base, cursor, row_ptr);
    k_bscatter<<<scB, 256, 2 * NB * sizeof(int), stream>>>(
        srcA, dstA, etype, E, NB, cursor, brec);
    k_bsort<<<NB, 256, 0, stream>>>(brec, base, N, row_ptr, csr);
    k_fused<<<(N + 15) / 16, 512, 0, stream>>>(xb, comp, row_ptr, csr, Wf, bias,
                                               (float*)d_out, N);
}